// Round 10
// baseline (1038.099 us; speedup 1.0000x reference)
//
#include <hip/hip_runtime.h>

typedef __attribute__((ext_vector_type(4))) float f32x4;
typedef __attribute__((ext_vector_type(4))) int i32x4;
typedef __attribute__((ext_vector_type(8))) short short8;
typedef __attribute__((ext_vector_type(4))) short short4v;
typedef unsigned short u16;
typedef unsigned int u32;
typedef unsigned long long u64;

#define DEV static __device__ __forceinline__

DEV float bf2f(u16 u){ union { unsigned int i; float f; } v; v.i = ((unsigned int)u) << 16; return v.f; }
DEV u16 f2bf(float f){ union { float f; unsigned int i; } v; v.f = f; unsigned int r = v.i + 0x7fffu + ((v.i >> 16) & 1u); return (u16)(r >> 16); }
DEV float sigm(float x){ return 1.f / (1.f + expf(-x)); }

// write-through (agent-coherent) stores
DEV void stg_f32(float* p, float v){ __hip_atomic_store(p, v, __ATOMIC_RELAXED, __HIP_MEMORY_SCOPE_AGENT); }
DEV void stg_u16(u16* p, u16 v){ __hip_atomic_store(p, v, __ATOMIC_RELAXED, __HIP_MEMORY_SCOPE_AGENT); }
DEV void stg_u32(u32* p, u32 v){ __hip_atomic_store(p, v, __ATOMIC_RELAXED, __HIP_MEMORY_SCOPE_AGENT); }
DEV void stg_u64(u64* p, u64 v){ __hip_atomic_store(p, v, __ATOMIC_RELAXED, __HIP_MEMORY_SCOPE_AGENT); }
DEV float ldg_f32(const float* p){ return __hip_atomic_load(p, __ATOMIC_RELAXED, __HIP_MEMORY_SCOPE_AGENT); }
DEV u32 ldg_u32(const u32* p){ return __hip_atomic_load(p, __ATOMIC_RELAXED, __HIP_MEMORY_SCOPE_AGENT); }
// cache-bypassing 16B ops (issue only; caller does s_waitcnt + sched_barrier)
DEV void ldcc4i(i32x4* d, const void* p){
    asm volatile("global_load_dwordx4 %0, %1, off sc0 sc1" : "=v"(*d) : "v"(p) : "memory");
}
DEV void ldcc4f(f32x4* d, const void* p){
    asm volatile("global_load_dwordx4 %0, %1, off sc0 sc1" : "=v"(*d) : "v"(p) : "memory");
}
DEV void stcc4f(void* p, f32x4 v){
    asm volatile("global_store_dwordx4 %0, %1, off sc0 sc1" :: "v"(p), "v"(v) : "memory");
}
DEV short8 as_s8(i32x4 v){ union{ i32x4 i; short8 s; } u; u.i = v; return u.s; }

DEV short8 cvt8(const float* __restrict__ p){
    const f32x4* q = (const f32x4*)p;
    f32x4 lo = q[0], hi = q[1];
    short8 r;
    r[0]=(short)f2bf(lo[0]); r[1]=(short)f2bf(lo[1]); r[2]=(short)f2bf(lo[2]); r[3]=(short)f2bf(lo[3]);
    r[4]=(short)f2bf(hi[0]); r[5]=(short)f2bf(hi[1]); r[6]=(short)f2bf(hi[2]); r[7]=(short)f2bf(hi[3]);
    return r;
}
DEV u64 pack4bf(f32x4 a){
    union { short4v s; u64 q; } u;
    u.s[0]=(short)f2bf(a[0]); u.s[1]=(short)f2bf(a[1]);
    u.s[2]=(short)f2bf(a[2]); u.s[3]=(short)f2bf(a[3]);
    return u.q;
}
DEV u64 pack2f(float a, float b){ union{ float f[2]; u64 q; } u; u.f[0]=a; u.f[1]=b; return u.q; }

// ---------------------------------------------------------------------------
// barriers: slot-per-block; wave0 polls; no L2 invalidation anywhere.
// ---------------------------------------------------------------------------
DEV void bar_post(u32* __restrict__ slots, u32 n, int bid, int tid)
{
    asm volatile("s_waitcnt vmcnt(0)" ::: "memory");
    __syncthreads();
    if (tid == 0)
        __hip_atomic_store(&slots[bid], n, __ATOMIC_RELAXED, __HIP_MEMORY_SCOPE_AGENT);
}
template<int SL>
DEV void bar_wait256(const u32* __restrict__ slots, u32 n, int tid)
{
    if (tid < 64) {
        for (;;) {
            bool ok = true;
#pragma unroll
            for (int c = 0; c < 4; ++c) {
                u32 v = __hip_atomic_load(&slots[tid*4+c], __ATOMIC_RELAXED, __HIP_MEMORY_SCOPE_AGENT);
                ok &= (v >= n);
            }
            if (__all(ok)) break;
            __builtin_amdgcn_s_sleep(SL);
        }
    }
    __syncthreads();
}
DEV void bar_wait64(const u32* __restrict__ slots, u32 n, int tid)
{
    if (tid < 64) {
        for (;;) {
            u32 v = __hip_atomic_load(&slots[tid], __ATOMIC_RELAXED, __HIP_MEMORY_SCOPE_AGENT);
            if (__all(v >= n)) break;
            __builtin_amdgcn_s_sleep(2);
        }
    }
    __syncthreads();
}

// ---------------------------------------------------------------------------
// k_all: one cooperative kernel. 256 blocks x 256 threads.
// A blocks (0-63): gates GEMM + LSTM, 64-slot barrier domain; block 0
//   publishes `gen` (own cacheline) for B after each detect.
// B blocks (64-191): attention; batched queue consumption of `gen` — never
//   touch the slot lines.
// idle blocks (192-255): straight to final barrier with big sleep.
// ---------------------------------------------------------------------------
#define WLDS_BYTES 131072
#define RED_PITCH 66
#define MLB_PITCH 1032
#define MLB_BYTES (32 * MLB_PITCH * 4)
#define DYN_BYTES (WLDS_BYTES + 2*32*RED_PITCH*4)

__global__ void __launch_bounds__(256, 1)
k_all(const int* __restrict__ tgt, const float* __restrict__ h0, const float* __restrict__ c0,
      const float* __restrict__ enc, const int* __restrict__ slen, const float* __restrict__ emb,
      const float* __restrict__ Wih, const float* __restrict__ Whh,
      const float* __restrict__ bih, const float* __restrict__ bhh,
      const float* __restrict__ Wai, const float* __restrict__ Wao,
      float* __restrict__ out,
      u16* __restrict__ Wih16, u16* __restrict__ Wao16, u16* __restrict__ enc16,
      u16* __restrict__ xrow, u16* __restrict__ WT, u16* __restrict__ xg2,
      float* __restrict__ Mf, u16* __restrict__ hb, float* __restrict__ hAllF,
      u16* __restrict__ hAll, u16* __restrict__ ctxA,
      float* __restrict__ pCtx, float* __restrict__ pMx, float* __restrict__ pSm,
      u32* __restrict__ bar)
{
    const int bid = blockIdx.x, tid = threadIdx.x;
    const int wv = tid >> 6, l = tid & 63, lr = l & 15, lq = l >> 4;
    u32* slots = bar;
    u32* genp  = bar + 384;          // own 128B line, single writer (A block 0)

    extern __shared__ char smem[];
    float* red = (float*)(smem + WLDS_BYTES);        // A: [2][32][RED_PITCH]
    float* MlB = (float*)smem;                       // B: [32][MLB_PITCH]
    float* hB  = (float*)(smem + MLB_BYTES);         // B: [1024]
    float* scb = (float*)(smem + MLB_BYTES + 4096);  // B: [32]
    float* pb  = (float*)(smem + MLB_BYTES + 4096 + 128); // B: [32]
    u16 (*tl)[65] = (u16(*)[65])smem;                // prep transpose tile
    __shared__ int genS;

    // ================= P0: prep (49 units per block) =================
    for (int u = bid; u < 12544; u += 256) {
        if (u < 10240) {
            const float* src; u16* dst; size_t i;
            if (u < 4096)      { src = Wih; dst = Wih16; i = (size_t)u * 1024 + tid * 4; }
            else if (u < 6144) { src = Wao; dst = Wao16; i = (size_t)(u - 4096) * 1024 + tid * 4; }
            else               { src = enc; dst = enc16; i = (size_t)(u - 6144) * 1024 + tid * 4; }
            f32x4 v = *(const f32x4*)(src + i);
            stg_u64((u64*)(dst + i), pack4bf(v));
        } else if (u < 12256) {
            int r = u - 10240;
            int t = r >> 5, b = r & 31;
            const float* src = emb + (size_t)tgt[b * 64 + t] * 1024;
            f32x4 v = *(const f32x4*)(src + tid * 4);
            stg_u64((u64*)(xrow + (size_t)r * 1024 + tid * 4), pack4bf(v));
        } else if (u < 12512) {
            int tb = u - 12256;
            int ti = tb >> 4, tj = tb & 15;
            int rr = tid >> 2, cc = (tid & 3) * 16;
            __syncthreads();
            for (int i = 0; i < 16; ++i)
                tl[rr][cc + i] = f2bf(Wai[(size_t)(ti * 64 + rr) * 1024 + tj * 64 + cc + i]);
            __syncthreads();
            for (int i4 = 0; i4 < 4; ++i4) {
                union { u16 s[4]; u64 q; } o;
#pragma unroll
                for (int k = 0; k < 4; ++k) o.s[k] = tl[cc + i4 * 4 + k][rr];
                stg_u64((u64*)(WT + (size_t)(tj * 64 + rr) * 1024 + ti * 64 + cc + i4 * 4), o.q);
            }
        } else {
            int b = u - 12512;
            int j = tid * 4;
            union { u16 s[4]; u64 q; } o;
#pragma unroll
            for (int i = 0; i < 4; ++i) {
                int k = j + i;
                float hv = (k < 512) ? h0[(size_t)b * 512 + k] : h0[(size_t)(32 + b) * 512 + (k - 512)];
                o.s[i] = f2bf(hv);
            }
            stg_u64((u64*)(hb + (size_t)b * 1024 + j), o.q);   // slot 0 = h_0
        }
    }
    bar_post(slots, 1, bid, tid);
    bar_wait256<4>(slots, 1, tid);

    // ================= P1: xg-GEMM (2048 tiles) + M-GEMM (1024 tiles) =================
    for (int tile = bid; tile < 3072; tile += 256) {
        if (tile < 2048) {
            const int mt = tile & 31, nt = tile >> 5;
            const int r0 = mt * 64 + wv * 16, n0 = nt * 64;
            int rr0 = r0 + lr; int rc = (rr0 < 2016) ? rr0 : 2015;
            const u16* arow = xrow + (size_t)rc * 1024;
            const u16* brow = Wih16 + (size_t)(n0 + lr) * 1024;
            f32x4 acc[4] = {{0,0,0,0},{0,0,0,0},{0,0,0,0},{0,0,0,0}};
            for (int k0 = 0; k0 < 1024; k0 += 32) {
                int ko = k0 + lq * 8;
                short8 av = *(const short8*)(arow + ko);
#pragma unroll
                for (int nf = 0; nf < 4; ++nf) {
                    short8 bv = *(const short8*)(brow + (size_t)nf * 16 * 1024 + ko);
                    acc[nf] = __builtin_amdgcn_mfma_f32_16x16x32_bf16(av, bv, acc[nf], 0, 0, 0);
                }
            }
#pragma unroll
            for (int nf = 0; nf < 4; ++nf) {
                int n = n0 + nf * 16 + lr;
                float bias = bih[n] + bhh[n];
                int gate = n >> 10, hc = n & 1023;
#pragma unroll
                for (int q = 0; q < 4; ++q) {
                    int rr = r0 + lq * 4 + q;
                    if (rr < 2016)
                        stg_u16(&xg2[((size_t)rr * 1024 + hc) * 4 + gate], f2bf(acc[nf][q] + bias));
                }
            }
        } else {
            const int mb = tile - 2048;
            const int mt = mb & 63, nt = mb >> 6;
            const int r0 = mt * 64 + wv * 16, n0 = nt * 64;
            const u16* arow = enc16 + (size_t)(r0 + lr) * 1024;
            const u16* brow = WT + (size_t)(n0 + lr) * 1024;
            f32x4 acc[4] = {{0,0,0,0},{0,0,0,0},{0,0,0,0},{0,0,0,0}};
            for (int k0 = 0; k0 < 1024; k0 += 32) {
                int ko = k0 + lq * 8;
                short8 av = *(const short8*)(arow + ko);
#pragma unroll
                for (int nf = 0; nf < 4; ++nf) {
                    short8 bv = *(const short8*)(brow + (size_t)nf * 16 * 1024 + ko);
                    acc[nf] = __builtin_amdgcn_mfma_f32_16x16x32_bf16(av, bv, acc[nf], 0, 0, 0);
                }
            }
#pragma unroll
            for (int nf = 0; nf < 4; ++nf) {
                int n = n0 + nf * 16 + lr;
#pragma unroll
                for (int q = 0; q < 4; ++q)
                    stg_f32(&Mf[(size_t)(r0 + lq * 4 + q) * 1024 + n], acc[nf][q]);
            }
        }
    }
    bar_post(slots, 2, bid, tid);
    bar_wait256<4>(slots, 2, tid);

    // ================= serial loop =================
    if (bid < 64) {
        // -------- group A: gates GEMM + LSTM, 64-block barrier domain --------
        const int g = bid;
        for (int u = tid; u < 8192; u += 256) {
            int row = u >> 7, c16 = u & 127;
            const float* src = Whh + ((size_t)((row >> 4) * 1024 + g * 16 + (row & 15))) * 1024 + c16 * 8;
            short8 w = cvt8(src);
            int byte = (row * 2048 + c16 * 16) ^ ((row & 7) << 4);
            *(short8*)(smem + byte) = w;
        }
        const int b = tid >> 3, jp = (tid & 7) * 2;
        const int hc = g * 16 + jp;
        float creg0 = (hc < 512) ? c0[(size_t)b * 512 + hc] : c0[(size_t)(32 + b) * 512 + hc - 512];
        float creg1 = (hc + 1 < 512) ? c0[(size_t)b * 512 + hc + 1] : c0[(size_t)(32 + b) * 512 + hc + 1 - 512];
        float xga[4], xgb[4];
        {
            f32x4 raw = *(const f32x4*)(xg2 + ((size_t)b * 1024 + hc) * 4);   // t=0
            union { f32x4 f; short8 s; } u; u.f = raw;
#pragma unroll
            for (int gt = 0; gt < 4; ++gt) { xga[gt] = bf2f((u16)u.s[gt]); xgb[gt] = bf2f((u16)u.s[4 + gt]); }
        }
        const int kw = wv & 1, nw = wv >> 1;
        __syncthreads();

        for (int t = 0; t < 63; ++t) {
            if (t > 0) {
                bar_wait64(slots, (u32)(t + 2), tid);
                if (g == 0 && tid == 0) stg_u32(genp, (u32)(t + 2));   // publish for B
            }

            const u16* hbase = hb + (size_t)(t & 1) * 32768;
            const u16* p0 = hbase + (size_t)lr * 1024 + kw * 512 + lq * 8;
            const u16* p1 = p0 + 16 * 1024;
            i32x4 ap0[8], ap1[8];
#pragma unroll
            for (int p = 0; p < 8; ++p) { ldcc4i(&ap0[p], p0 + p * 32); ldcc4i(&ap1[p], p1 + p * 32); }
            f32x4 acc00 = {0,0,0,0}, acc01 = {0,0,0,0}, acc10 = {0,0,0,0}, acc11 = {0,0,0,0};
#pragma unroll
            for (int ks = 0; ks < 16; ++ks) {
                int n0r = nw * 32 + lr;
                int kbyte = (kw * 512 + ks * 32 + lq * 8) * 2;
                short8 bv0 = *(const short8*)(smem + ((n0r * 2048 + kbyte) ^ ((n0r & 7) << 4)));
                int n1r = n0r + 16;
                short8 bv1 = *(const short8*)(smem + ((n1r * 2048 + kbyte) ^ ((n1r & 7) << 4)));
                if (ks <= 8) { asm volatile("s_waitcnt vmcnt(14)" ::: "memory"); }
                else         { asm volatile("s_waitcnt vmcnt(%0)" :: "i"(2 * (15 - ks)) : "memory"); }
                __builtin_amdgcn_sched_barrier(0);
                short8 a0 = as_s8(ap0[ks & 7]), a1 = as_s8(ap1[ks & 7]);
                acc00 = __builtin_amdgcn_mfma_f32_16x16x32_bf16(a0, bv0, acc00, 0, 0, 0);
                acc10 = __builtin_amdgcn_mfma_f32_16x16x32_bf16(a1, bv0, acc10, 0, 0, 0);
                acc01 = __builtin_amdgcn_mfma_f32_16x16x32_bf16(a0, bv1, acc01, 0, 0, 0);
                acc11 = __builtin_amdgcn_mfma_f32_16x16x32_bf16(a1, bv1, acc11, 0, 0, 0);
                if (ks < 8) { ldcc4i(&ap0[ks & 7], p0 + (ks + 8) * 32); ldcc4i(&ap1[ks & 7], p1 + (ks + 8) * 32); }
            }
#pragma unroll
            for (int q = 0; q < 4; ++q) {
                red[(kw * 32 + lq * 4 + q) * RED_PITCH + nw * 32 + lr]       = acc00[q];
                red[(kw * 32 + 16 + lq * 4 + q) * RED_PITCH + nw * 32 + lr]  = acc10[q];
                red[(kw * 32 + lq * 4 + q) * RED_PITCH + nw * 32 + 16 + lr]      = acc01[q];
                red[(kw * 32 + 16 + lq * 4 + q) * RED_PITCH + nw * 32 + 16 + lr] = acc11[q];
            }
            __syncthreads();

            float G0[4], G1[4];
#pragma unroll
            for (int gt = 0; gt < 4; ++gt) {
                int n = gt * 16 + jp;
                G0[gt] = red[b * RED_PITCH + n] + red[(32 + b) * RED_PITCH + n] + xga[gt];
                G1[gt] = red[b * RED_PITCH + n + 1] + red[(32 + b) * RED_PITCH + n + 1] + xgb[gt];
            }
            float cn0 = sigm(G0[1]) * creg0 + sigm(G0[0]) * tanhf(G0[2]);
            float hn0 = sigm(G0[3]) * tanhf(cn0);
            float cn1 = sigm(G1[1]) * creg1 + sigm(G1[0]) * tanhf(G1[2]);
            float hn1 = sigm(G1[3]) * tanhf(cn1);
            creg0 = cn0; creg1 = cn1;
            u16 hb0 = f2bf(hn0), hb1 = f2bf(hn1);
            u32 hpair = (u32)hb0 | ((u32)hb1 << 16);
            stg_u32((u32*)&hb[(size_t)((t + 1) & 1) * 32768 + b * 1024 + hc], hpair);
            stg_u32((u32*)&hAll[((size_t)t * 32 + b) * 1024 + hc], hpair);
            stg_u64((u64*)&hAllF[((size_t)t * 32 + b) * 1024 + hc], pack2f(hn0, hn1));
            if (t == 62)
                stg_u64((u64*)&out[2064384 + b * 1024 + hc], pack2f(hn0, hn1));

            bar_post(slots, (u32)(t + 3), bid, tid);
            __syncthreads();   // red reuse protection

            if (t < 62) {
                f32x4 raw = *(const f32x4*)(xg2 + ((size_t)((t + 1) * 32 + b) * 1024 + hc) * 4);
                union { f32x4 f; short8 s; } u; u.f = raw;
#pragma unroll
                for (int gt = 0; gt < 4; ++gt) { xga[gt] = bf2f((u16)u.s[gt]); xgb[gt] = bf2f((u16)u.s[4 + gt]); }
            }
        }
        // block 0: final gen publish so B can finish step 62
        if (g == 0) {
            bar_wait64(slots, 65u, tid);
            if (tid == 0) stg_u32(genp, 65u);
        }
        stg_u64((u64*)&out[2064384 + 32768 + b * 1024 + hc], pack2f(creg0, creg1));
    } else if (bid < 192) {
        // -------- group B: attention; batched consumption of gen --------
        const int idx = bid - 64;
        const int b = idx >> 2, q = idx & 3;
        int vlen = slen[b]; if (vlen < 1) vlen = 1;
        const int tj = l & 15, sg4 = l >> 4;
        for (int u = tid; u < 8192; u += 256) {
            int row = u >> 8, c = (u & 255) * 4;
            *(f32x4*)(MlB + row * MLB_PITCH + c) =
                *(const f32x4*)(Mf + ((size_t)(b * 128 + q * 32 + row)) * 1024 + c);
        }
        __syncthreads();

        int done = 0;
        while (done < 63) {
            if (tid == 0) genS = (int)ldg_u32(genp);
            __syncthreads();
            int avail = genS - 3;               // highest completed step index
            if (avail > 62) avail = 62;
            __syncthreads();                    // genS stable before next rewrite
            if (avail < done) { __builtin_amdgcn_s_sleep(16); continue; }

            for (int s = done; s <= avail; ++s) {
                {
                    f32x4 hv;
                    ldcc4f(&hv, hAllF + ((size_t)s * 32 + b) * 1024 + tid * 4);
                    asm volatile("s_waitcnt vmcnt(0)" ::: "memory");
                    __builtin_amdgcn_sched_barrier(0);
                    *(f32x4*)&hB[tid * 4] = hv;
                }
                __syncthreads();
#pragma unroll
                for (int rr2 = 0; rr2 < 2; ++rr2) {
                    int lrow = wv * 8 + rr2 * 4 + sg4;
                    const float* Mrow = MlB + (size_t)lrow * MLB_PITCH;
                    float sc = 0.f;
#pragma unroll
                    for (int it = 0; it < 16; ++it) {
                        int j = it * 64 + tj * 4;
                        f32x4 m4 = *(const f32x4*)(Mrow + j);
                        f32x4 h4 = *(const f32x4*)&hB[j];
                        sc += m4[0]*h4[0] + m4[1]*h4[1] + m4[2]*h4[2] + m4[3]*h4[3];
                    }
                    sc += __shfl_xor(sc, 1);
                    sc += __shfl_xor(sc, 2);
                    sc += __shfl_xor(sc, 4);
                    sc += __shfl_xor(sc, 8);
                    if (tj == 0) scb[lrow] = (q * 32 + lrow < vlen) ? sc : -1e30f;
                }
                __syncthreads();
                if (tid < 64) {
                    float a = (tid < 32) ? scb[tid] : -1e30f;
                    float m = a;
#pragma unroll
                    for (int d = 1; d < 64; d <<= 1) m = fmaxf(m, __shfl_xor(m, d));
                    float e = (tid < 32 && a > -1e29f) ? expf(a - m) : 0.f;
                    float ssum = e;
#pragma unroll
                    for (int d = 1; d < 64; d <<= 1) ssum += __shfl_xor(ssum, d);
                    if (tid < 32) pb[tid] = e;
                    if (tid == 0) {
                        stg_f32(&pMx[((size_t)s * 32 + b) * 4 + q], m);
                        stg_f32(&pSm[((size_t)s * 32 + b) * 4 + q], ssum);
                    }
                }
                __syncthreads();
                f32x4 ca = {0.f, 0.f, 0.f, 0.f};
                const u16* eb = enc16 + ((size_t)(b * 128 + q * 32)) * 1024 + tid * 4;
#pragma unroll
                for (int r = 0; r < 32; ++r) {
                    float p = pb[r];
                    short4v e4 = *(const short4v*)(eb + (size_t)r * 1024);
                    ca[0] += p * bf2f((u16)e4[0]);
                    ca[1] += p * bf2f((u16)e4[1]);
                    ca[2] += p * bf2f((u16)e4[2]);
                    ca[3] += p * bf2f((u16)e4[3]);
                }
                stcc4f(pCtx + (((size_t)s * 32 + b) * 4 + q) * 1024 + tid * 4, ca);
            }
            done = avail + 1;
        }
    }
    bar_post(slots, 66, bid, tid);
    bar_wait256<64>(slots, 66, tid);

    // ================= P2a: combine chunk partials -> ctxA =================
    for (int r = bid; r < 2016; r += 256) {
        float m4[4], s4[4];
#pragma unroll
        for (int c = 0; c < 4; ++c) { m4[c] = ldg_f32(pMx + (size_t)r * 4 + c); s4[c] = ldg_f32(pSm + (size_t)r * 4 + c); }
        float gm = fmaxf(fmaxf(m4[0], m4[1]), fmaxf(m4[2], m4[3]));
        float e[4], ws = 0.f;
#pragma unroll
        for (int c = 0; c < 4; ++c) { e[c] = expf(m4[c] - gm); ws += s4[c] * e[c]; }
        float inv = 1.f / ws;
        f32x4 pc[4];
#pragma unroll
        for (int c = 0; c < 4; ++c) ldcc4f(&pc[c], pCtx + ((size_t)r * 4 + c) * 1024 + tid * 4);
        asm volatile("s_waitcnt vmcnt(0)" ::: "memory");
        __builtin_amdgcn_sched_barrier(0);
        f32x4 a = {0.f, 0.f, 0.f, 0.f};
#pragma unroll
        for (int c = 0; c < 4; ++c) {
            float sc = e[c] * inv;
            a[0] += pc[c][0] * sc; a[1] += pc[c][1] * sc; a[2] += pc[c][2] * sc; a[3] += pc[c][3] * sc;
        }
        stg_u64((u64*)(ctxA + (size_t)r * 1024 + tid * 4), pack4bf(a));
    }
    bar_post(slots, 67, bid, tid);
    bar_wait256<4>(slots, 67, tid);

    // ================= P2b: output GEMM (512 tiles, 2 per block) =================
    for (int tile = bid; tile < 512; tile += 256) {
        const int mt = tile & 31, nt = tile >> 5;
        const int r0 = mt * 64 + wv * 16, n0 = nt * 64;
        int rr0 = r0 + lr; int rc = (rr0 < 2016) ? rr0 : 2015;
        const u16* arc = ctxA + (size_t)rc * 1024;
        const u16* arh = hAll + (size_t)rc * 1024;
        const u16* brow = Wao16 + (size_t)(n0 + lr) * 2048;
        f32x4 acc[4] = {{0,0,0,0},{0,0,0,0},{0,0,0,0},{0,0,0,0}};
        for (int k0 = 0; k0 < 2048; k0 += 32) {
            int ko = k0 + lq * 8;
            short8 av = (k0 < 1024) ? *(const short8*)(arc + ko)
                                    : *(const short8*)(arh + (ko - 1024));
#pragma unroll
            for (int nf = 0; nf < 4; ++nf) {
                short8 bv = *(const short8*)(brow + (size_t)nf * 16 * 2048 + ko);
                acc[nf] = __builtin_amdgcn_mfma_f32_16x16x32_bf16(av, bv, acc[nf], 0, 0, 0);
            }
        }
#pragma unroll
        for (int nf = 0; nf < 4; ++nf) {
            int n = n0 + nf * 16 + lr;
#pragma unroll
            for (int q = 0; q < 4; ++q) {
                int rr = r0 + lq * 4 + q;
                if (rr < 2016) {
                    int t = rr >> 5, b = rr & 31;
                    out[(size_t)b * 64512 + t * 1024 + n] = tanhf(acc[nf][q]);
                }
            }
        }
    }
}

// ---------------------------------------------------------------------------
extern "C" void kernel_launch(void* const* d_in, const int* in_sizes, int n_in,
                              void* d_out, int out_size, void* d_ws, size_t ws_size,
                              hipStream_t stream)
{
    (void)in_sizes; (void)n_in; (void)out_size; (void)ws_size;
    const int*   tgt  = (const int*)d_in[0];
    const float* h0   = (const float*)d_in[1];
    const float* c0   = (const float*)d_in[2];
    const float* enc  = (const float*)d_in[3];
    const int*   slen = (const int*)d_in[4];
    const float* emb  = (const float*)d_in[5];
    const float* Wih  = (const float*)d_in[6];
    const float* Whh  = (const float*)d_in[7];
    const float* bih  = (const float*)d_in[8];
    const float* bhh  = (const float*)d_in[9];
    const float* Wai  = (const float*)d_in[10];
    const float* Wao  = (const float*)d_in[11];
    float* out = (float*)d_out;

    char* ws = (char*)d_ws;
    size_t off = 0;
    auto alloc = [&](size_t bytes) -> char* {
        char* p = ws + off; off += (bytes + 255) & ~(size_t)255; return p;
    };
    u16*   Wih16 = (u16*)  alloc(4096UL * 1024 * 2);
    u16*   Wao16 = (u16*)  alloc(1024UL * 2048 * 2);
    u16*   enc16 = (u16*)  alloc(4096UL * 1024 * 2);
    u16*   xrow  = (u16*)  alloc(2016UL * 1024 * 2);
    u16*   WT    = (u16*)  alloc(1024UL * 1024 * 2);
    u16*   xg2   = (u16*)  alloc(2016UL * 1024 * 4 * 2);
    float* Mf    = (float*)alloc(4096UL * 1024 * 4);
    u16*   hb    = (u16*)  alloc(2UL * 32 * 1024 * 2);
    float* hAllF = (float*)alloc(2016UL * 1024 * 4);
    u16*   hAll  = (u16*)  alloc(2016UL * 1024 * 2);
    u16*   ctxA  = (u16*)  alloc(2016UL * 1024 * 2);
    float* pCtx  = (float*)alloc(2016UL * 4 * 1024 * 4);
    float* pMx   = (float*)alloc(2016UL * 4 * 4);
    float* pSm   = (float*)alloc(2016UL * 4 * 4);
    u32*   bar   = (u32*)  alloc(2048);

    static int lds_set = 0;
    if (!lds_set) {
        (void)hipFuncSetAttribute((const void*)k_all,
                                  hipFuncAttributeMaxDynamicSharedMemorySize, DYN_BYTES);
        lds_set = 1;
    }

    hipMemsetAsync(bar, 0, 2048, stream);
    void* kargs[] = { (void*)&tgt, (void*)&h0, (void*)&c0, (void*)&enc, (void*)&slen, (void*)&emb,
                      (void*)&Wih, (void*)&Whh, (void*)&bih, (void*)&bhh, (void*)&Wai, (void*)&Wao,
                      (void*)&out,
                      (void*)&Wih16, (void*)&Wao16, (void*)&enc16, (void*)&xrow, (void*)&WT,
                      (void*)&xg2, (void*)&Mf, (void*)&hb, (void*)&hAllF, (void*)&hAll, (void*)&ctxA,
                      (void*)&pCtx, (void*)&pMx, (void*)&pSm, (void*)&bar };
    hipLaunchCooperativeKernel((const void*)k_all, dim3(256), dim3(256), kargs, DYN_BYTES, stream);
}

// Round 12
// 749.207 us; speedup vs baseline: 1.3856x; 1.3856x over previous
//
#include <hip/hip_runtime.h>

typedef __attribute__((ext_vector_type(4))) float f32x4;
typedef __attribute__((ext_vector_type(4))) int i32x4;
typedef __attribute__((ext_vector_type(8))) short short8;
typedef __attribute__((ext_vector_type(4))) short short4v;
typedef unsigned short u16;
typedef unsigned int u32;
typedef unsigned long long u64;

#define DEV static __device__ __forceinline__

DEV float bf2f(u16 u){ union { unsigned int i; float f; } v; v.i = ((unsigned int)u) << 16; return v.f; }
DEV u16 f2bf(float f){ union { float f; unsigned int i; } v; v.f = f; unsigned int r = v.i + 0x7fffu + ((v.i >> 16) & 1u); return (u16)(r >> 16); }
DEV float sigm(float x){ return 1.f / (1.f + expf(-x)); }

// write-through (agent-coherent) stores
DEV void stg_f32(float* p, float v){ __hip_atomic_store(p, v, __ATOMIC_RELAXED, __HIP_MEMORY_SCOPE_AGENT); }
DEV void stg_u16(u16* p, u16 v){ __hip_atomic_store(p, v, __ATOMIC_RELAXED, __HIP_MEMORY_SCOPE_AGENT); }
DEV void stg_u64(u64* p, u64 v){ __hip_atomic_store(p, v, __ATOMIC_RELAXED, __HIP_MEMORY_SCOPE_AGENT); }
// coherent reads (relaxed, agent scope)
DEV u64 ldg_u64(const u64* p){ return __hip_atomic_load(p, __ATOMIC_RELAXED, __HIP_MEMORY_SCOPE_AGENT); }
DEV float ldg_f32(const float* p){ return __hip_atomic_load(p, __ATOMIC_RELAXED, __HIP_MEMORY_SCOPE_AGENT); }
// cache-bypassing 16B load (issue only; caller does s_waitcnt + sched_barrier)
DEV void ldcc4i(i32x4* d, const void* p){
    asm volatile("global_load_dwordx4 %0, %1, off sc0 sc1" : "=v"(*d) : "v"(p) : "memory");
}
DEV void ldcc4f(f32x4* d, const void* p){
    asm volatile("global_load_dwordx4 %0, %1, off sc0 sc1" : "=v"(*d) : "v"(p) : "memory");
}
DEV short8 as_s8(i32x4 v){ union{ i32x4 i; short8 s; } u; u.i = v; return u.s; }

DEV short8 cvt8(const float* __restrict__ p){
    const f32x4* q = (const f32x4*)p;
    f32x4 lo = q[0], hi = q[1];
    short8 r;
    r[0]=(short)f2bf(lo[0]); r[1]=(short)f2bf(lo[1]); r[2]=(short)f2bf(lo[2]); r[3]=(short)f2bf(lo[3]);
    r[4]=(short)f2bf(hi[0]); r[5]=(short)f2bf(hi[1]); r[6]=(short)f2bf(hi[2]); r[7]=(short)f2bf(hi[3]);
    return r;
}

// ---------------------------------------------------------------------------
// Distributed grid barrier (no L2 invalidation; shared data read sc0/sc1).
// ---------------------------------------------------------------------------
DEV void bar_arrive(u32* __restrict__ slots, u32 n, int bid, int tid)
{
    asm volatile("s_waitcnt vmcnt(0)" ::: "memory");
    __syncthreads();
    if (tid == 0)
        __hip_atomic_store(&slots[bid], n, __ATOMIC_RELAXED, __HIP_MEMORY_SCOPE_AGENT);
}

DEV void bar_wait(u32* __restrict__ slots, u32 n, int tid)
{
    if (tid < 64) {
        for (;;) {
            u32 v0 = __hip_atomic_load(&slots[tid*4+0], __ATOMIC_RELAXED, __HIP_MEMORY_SCOPE_AGENT);
            u32 v1 = __hip_atomic_load(&slots[tid*4+1], __ATOMIC_RELAXED, __HIP_MEMORY_SCOPE_AGENT);
            u32 v2 = __hip_atomic_load(&slots[tid*4+2], __ATOMIC_RELAXED, __HIP_MEMORY_SCOPE_AGENT);
            u32 v3 = __hip_atomic_load(&slots[tid*4+3], __ATOMIC_RELAXED, __HIP_MEMORY_SCOPE_AGENT);
            bool ok = (v0 >= n) && (v1 >= n) && (v2 >= n) && (v3 >= n);
            if (__all(ok)) break;
            __builtin_amdgcn_s_sleep(1);
        }
    }
    __syncthreads();
}

// ---------------------------------------------------------------------------
// k_prep: fused one-shot prep.
//   [0,4096)      cvt Wih  -> Wih16
//   [4096,6144)   cvt Wao  -> Wao16
//   [6144,10240)  cvt enc  -> enc16
//   [10240,12256) gather emb rows -> xrow (bf16)
//   [12256,12512) transpose W_attn_in -> WT (bf16)
//   [12512,12544) init cF (fp32), hb buf0 (bf16)
// ---------------------------------------------------------------------------
__global__ void __launch_bounds__(256)
k_prep(const float* __restrict__ Wih, u16* __restrict__ Wih16,
       const float* __restrict__ Wao, u16* __restrict__ Wao16,
       const float* __restrict__ enc, u16* __restrict__ enc16,
       const int* __restrict__ tgt, const float* __restrict__ emb, u16* __restrict__ xrow,
       const float* __restrict__ Wai, u16* __restrict__ WT,
       const float* __restrict__ h0, const float* __restrict__ c0,
       float* __restrict__ cF, u16* __restrict__ hb)
{
    const int bid = blockIdx.x, tid = threadIdx.x;
    __shared__ u16 tl[64][65];
    if (bid < 10240) {
        const float* src; u16* dst; int i;
        if (bid < 4096)      { src = Wih; dst = Wih16; i = bid * 1024 + tid * 4; }
        else if (bid < 6144) { src = Wao; dst = Wao16; i = (bid - 4096) * 1024 + tid * 4; }
        else                 { src = enc; dst = enc16; i = (bid - 6144) * 1024 + tid * 4; }
        f32x4 v = *(const f32x4*)(src + i);
        short4v o;
        o[0]=(short)f2bf(v[0]); o[1]=(short)f2bf(v[1]);
        o[2]=(short)f2bf(v[2]); o[3]=(short)f2bf(v[3]);
        *(short4v*)(dst + i) = o;
    } else if (bid < 12256) {
        int r = bid - 10240;
        int t = r >> 5, b = r & 31;
        const float* src = emb + (size_t)tgt[b * 64 + t] * 1024;
        int j = tid * 4;
        f32x4 v = *(const f32x4*)(src + j);
        short4v o;
        o[0]=(short)f2bf(v[0]); o[1]=(short)f2bf(v[1]);
        o[2]=(short)f2bf(v[2]); o[3]=(short)f2bf(v[3]);
        *(short4v*)(xrow + (size_t)r * 1024 + j) = o;
    } else if (bid < 12512) {
        int tb = bid - 12256;
        int ti = tb >> 4, tj = tb & 15;
        int rr = tid >> 2, cc = (tid & 3) * 16;
        for (int i = 0; i < 16; ++i)
            tl[rr][cc + i] = f2bf(Wai[(size_t)(ti * 64 + rr) * 1024 + tj * 64 + cc + i]);
        __syncthreads();
        for (int i = 0; i < 16; ++i)
            WT[(size_t)(tj * 64 + rr) * 1024 + ti * 64 + cc + i] = tl[cc + i][rr];
    } else {
        int b = bid - 12512;
        int j = tid * 4;
        for (int i = 0; i < 4; ++i) {
            int k = j + i;
            float hv = (k < 512) ? h0[(size_t)b * 512 + k] : h0[(size_t)(32 + b) * 512 + (k - 512)];
            float cv = (k < 512) ? c0[(size_t)b * 512 + k] : c0[(size_t)(32 + b) * 512 + (k - 512)];
            cF[b * 1024 + k] = cv;
            hb[b * 1024 + k] = f2bf(hv);
        }
    }
}

// ---------------------------------------------------------------------------
// k_mm: fused xg-GEMM [0,2048) and M-GEMM [2048,3072)
// ---------------------------------------------------------------------------
__global__ void __launch_bounds__(256)
k_mm(const u16* __restrict__ xrow, const u16* __restrict__ Wih16,
     const float* __restrict__ bih, const float* __restrict__ bhh, u16* __restrict__ xg,
     const u16* __restrict__ enc16, const u16* __restrict__ WT, float* __restrict__ Mf)
{
    const int tid = threadIdx.x;
    const int wv = tid >> 6, l = tid & 63, lr = l & 15, lq = l >> 4;
    if (blockIdx.x < 2048) {
        const int bid = blockIdx.x;
        const int mt = bid & 31, nt = bid >> 5;
        const int r0 = mt * 64 + wv * 16;
        const int n0 = nt * 64;
        int r = r0 + lr;
        int rc = (r < 2016) ? r : 2015;
        const u16* arow = xrow + (size_t)rc * 1024;
        const u16* brow = Wih16 + (size_t)(n0 + lr) * 1024;
        f32x4 acc[4] = {{0,0,0,0},{0,0,0,0},{0,0,0,0},{0,0,0,0}};
        for (int k0 = 0; k0 < 1024; k0 += 32) {
            int ko = k0 + lq * 8;
            short8 av = *(const short8*)(arow + ko);
#pragma unroll
            for (int nf = 0; nf < 4; ++nf) {
                short8 bv = *(const short8*)(brow + (size_t)nf * 16 * 1024 + ko);
                acc[nf] = __builtin_amdgcn_mfma_f32_16x16x32_bf16(av, bv, acc[nf], 0, 0, 0);
            }
        }
#pragma unroll
        for (int nf = 0; nf < 4; ++nf) {
            int n = n0 + nf * 16 + lr;
            float bias = bih[n] + bhh[n];
#pragma unroll
            for (int q = 0; q < 4; ++q) {
                int rr = r0 + lq * 4 + q;
                if (rr < 2016) xg[(size_t)rr * 4096 + n] = f2bf(acc[nf][q] + bias);
            }
        }
    } else {
        const int bid = blockIdx.x - 2048;
        const int mt = bid & 63, nt = bid >> 6;
        const int r0 = mt * 64 + wv * 16;
        const int n0 = nt * 64;
        const u16* arow = enc16 + (size_t)(r0 + lr) * 1024;
        const u16* brow = WT + (size_t)(n0 + lr) * 1024;
        f32x4 acc[4] = {{0,0,0,0},{0,0,0,0},{0,0,0,0},{0,0,0,0}};
        for (int k0 = 0; k0 < 1024; k0 += 32) {
            int ko = k0 + lq * 8;
            short8 av = *(const short8*)(arow + ko);
#pragma unroll
            for (int nf = 0; nf < 4; ++nf) {
                short8 bv = *(const short8*)(brow + (size_t)nf * 16 * 1024 + ko);
                acc[nf] = __builtin_amdgcn_mfma_f32_16x16x32_bf16(av, bv, acc[nf], 0, 0, 0);
            }
        }
#pragma unroll
        for (int nf = 0; nf < 4; ++nf) {
            int n = n0 + nf * 16 + lr;
#pragma unroll
            for (int q = 0; q < 4; ++q)
                Mf[(size_t)(r0 + lq * 4 + q) * 1024 + n] = acc[nf][q];
        }
    }
}

// ---------------------------------------------------------------------------
// combine 16 half-chunk partials -> ctxA[tstore] (tid<32)
// ---------------------------------------------------------------------------
DEV void combine16(int b, int ch, int tstore, int tid, int slot,
                   const float* __restrict__ pCtx, const float* __restrict__ pMx,
                   const float* __restrict__ pSm, u16* __restrict__ ctxA)
{
    if (tid >= 32) return;
    const float* mx = pMx + (size_t)slot * 512 + b * 16;
    const float* sm = pSm + (size_t)slot * 512 + b * 16;
    const float* pc = pCtx + (size_t)slot * (32 * 16 * 1024) + (size_t)b * 16 * 1024;
    float m16[16], s16[16];
#pragma unroll
    for (int c = 0; c < 16; ++c) { m16[c] = ldg_f32(mx + c); s16[c] = ldg_f32(sm + c); }
    float gm = -1e30f;
#pragma unroll
    for (int c = 0; c < 16; ++c) gm = fmaxf(gm, m16[c]);
    float wsum = 0.f, e[16];
#pragma unroll
    for (int c = 0; c < 16; ++c) { e[c] = expf(m16[c] - gm); wsum += s16[c] * e[c]; }
    float inv = 1.f / wsum;
    int j = ch * 128 + tid * 4;
    f32x4 a = {0.f, 0.f, 0.f, 0.f};
#pragma unroll
    for (int c = 0; c < 16; ++c) {
        union { u64 q[2]; f32x4 v; } u;
        const u64* p = (const u64*)(pc + (size_t)c * 1024 + j);
        u.q[0] = ldg_u64(p); u.q[1] = ldg_u64(p + 1);
        float s = e[c] * inv;
        a[0] += u.v[0] * s; a[1] += u.v[1] * s; a[2] += u.v[2] * s; a[3] += u.v[3] * s;
    }
    short4v o4;
    o4[0] = (short)f2bf(a[0]); o4[1] = (short)f2bf(a[1]);
    o4[2] = (short)f2bf(a[2]); o4[3] = (short)f2bf(a[3]);
    *(short4v*)(ctxA + ((size_t)tstore * 32 + b) * 1024 + j) = o4;
}

// ---------------------------------------------------------------------------
// k_loop: wave-specialized persistent kernel.
//   waves 0-1: gates GEMM — W_hh fragment in REGISTERS, A-loads 16-deep pipeline
//   waves 2-3: attention (in-wave softmax) then LSTM
//   shadow after arrive: combine(t-2) + xg prefetch
// ---------------------------------------------------------------------------
#define ML_PITCH 1028
#define EL_PITCH 1032
#define ML_BYTES (16 * ML_PITCH * 4)
#define EL_BYTES (16 * EL_PITCH * 2)
#define DYN_BYTES (ML_BYTES + EL_BYTES)

__global__ void __launch_bounds__(256, 1)
k_loop(const u16* __restrict__ xg, const float* __restrict__ Mf,
       u16* __restrict__ ctxA, u16* __restrict__ hAll,
       u16* __restrict__ hb, float* __restrict__ hF, float* __restrict__ cF,
       float* __restrict__ pCtx, float* __restrict__ pMx, float* __restrict__ pSm,
       const float* __restrict__ enc, const float* __restrict__ Whh,
       const int* __restrict__ slen, float* __restrict__ out, u32* __restrict__ bar)
{
    const int bid = blockIdx.x, tid = threadIdx.x;
    const int wv = tid >> 6, l = tid & 63, lr = l & 15, lq = l >> 4;
    u32* slots = bar;

    extern __shared__ char smem[];
    float* Ml = (float*)smem;                 // [16][ML_PITCH]
    u16*   El = (u16*)(smem + ML_BYTES);      // [16][EL_PITCH]

    __shared__ float red[2][32][16];

    const int b_at = bid >> 3, ch = bid & 7, s0 = ch * 16;

    // ---- prologue ----
    // GEMM waves: W_hh fragment -> registers (16 x short8 per wave)
    short8 breg[16];
    if (wv < 2) {
        const float* wsrc = Whh + ((size_t)((lr >> 2) * 1024 + bid * 4 + (lr & 3))) * 1024
                                + wv * 512 + lq * 8;
#pragma unroll
        for (int ks = 0; ks < 16; ++ks)
            breg[ks] = cvt8(wsrc + ks * 32);
    }
    {   // M slice (fp32)
        int row = tid >> 4;
        const float* src = Mf + (size_t)(b_at * 128 + s0 + row) * 1024;
        float* dst = &Ml[row * ML_PITCH];
#pragma unroll
        for (int i = 0; i < 16; ++i) {
            int c = (tid & 15) * 4 + i * 64;
            *(f32x4*)(dst + c) = *(const f32x4*)(src + c);
        }
    }
    {   // enc slice (bf16)
        int row = tid >> 4;
        const float* src = enc + (size_t)(b_at * 128 + s0 + row) * 1024;
        u16* dst = &El[row * EL_PITCH];
#pragma unroll
        for (int i = 0; i < 16; ++i) {
            int c = (tid & 15) * 4 + i * 64;
            f32x4 v = *(const f32x4*)(src + c);
            short4v o;
            o[0]=(short)f2bf(v[0]); o[1]=(short)f2bf(v[1]);
            o[2]=(short)f2bf(v[2]); o[3]=(short)f2bf(v[3]);
            *(short4v*)(dst + c) = o;
        }
    }

    // LSTM locals (tid in [128,256)): batch lb, hidden col lkidx
    const int lb = tid & 31, lkk = (tid >> 5) - 4;
    const int lkidx = bid * 4 + lkk;
    float creg = 0.f;
    float xgv[4] = {0,0,0,0};
    if (tid >= 128) {
        creg = cF[lb * 1024 + lkidx];
#pragma unroll
        for (int g = 0; g < 4; ++g)
            xgv[g] = bf2f(xg[((size_t)lb) * 4096 + g * 1024 + lkidx]);   // t=0
    }
    int vlen = slen[b_at]; if (vlen < 1) vlen = 1;
    __syncthreads();

    for (int t = 0; t < 64; ++t) {
        if (t >= 1) bar_wait(slots, (u32)t, tid);

        if (t < 63 && wv < 2) {
            // ---- gates GEMM (waves 0-1, K split 2-way, 16-deep pipeline) ----
            const u16* hrd = hb + (size_t)(t & 1) * (32 * 1024);
            const u16* p0 = hrd + lr * 1024 + wv * 512 + lq * 8;
            const u16* p1 = p0 + 16 * 1024;
            i32x4 a0b[16], a1b[16];
#pragma unroll
            for (int ks = 0; ks < 16; ++ks) {
                ldcc4i(&a0b[ks], p0 + ks * 32);
                ldcc4i(&a1b[ks], p1 + ks * 32);
            }
            f32x4 acc0 = {0,0,0,0}, acc1 = {0,0,0,0};
#pragma unroll
            for (int ks = 0; ks < 16; ++ks) {
                asm volatile("s_waitcnt vmcnt(%0)" :: "i"(30 - 2 * ks) : "memory");
                __builtin_amdgcn_sched_barrier(0);
                acc0 = __builtin_amdgcn_mfma_f32_16x16x32_bf16(as_s8(a0b[ks]), breg[ks], acc0, 0, 0, 0);
                acc1 = __builtin_amdgcn_mfma_f32_16x16x32_bf16(as_s8(a1b[ks]), breg[ks], acc1, 0, 0, 0);
            }
#pragma unroll
            for (int q = 0; q < 4; ++q) {
                red[wv][lq * 4 + q][lr] = acc0[q];
                red[wv][16 + lq * 4 + q][lr] = acc1[q];
            }
        }

        if (t >= 1 && wv >= 2) {
            // ---- attention for h_t (waves 2-3, fully in-wave) ----
            const int w = wv - 2;
            const int lane = l;
            const float* hrow = hF + (size_t)(t & 1) * (32 * 1024) + b_at * 1024;
            f32x4 hreg[4];
            ldcc4f(&hreg[0], hrow + 0 * 256 + lane * 4);
            ldcc4f(&hreg[1], hrow + 1 * 256 + lane * 4);
            ldcc4f(&hreg[2], hrow + 2 * 256 + lane * 4);
            ldcc4f(&hreg[3], hrow + 3 * 256 + lane * 4);
            asm volatile("s_waitcnt vmcnt(0)" ::: "memory");
            __builtin_amdgcn_sched_barrier(0);
            float part[8];
#pragma unroll
            for (int r = 0; r < 8; ++r) {
                const float* mrow = &Ml[(w * 8 + r) * ML_PITCH];
                float s = 0.f;
#pragma unroll
                for (int c = 0; c < 4; ++c) {
                    f32x4 m4 = *(const f32x4*)(mrow + c * 256 + lane * 4);
                    s += m4[0]*hreg[c][0] + m4[1]*hreg[c][1] + m4[2]*hreg[c][2] + m4[3]*hreg[c][3];
                }
                part[r] = s;
            }
#pragma unroll
            for (int d = 1; d < 64; d <<= 1) {
#pragma unroll
                for (int r = 0; r < 8; ++r) part[r] += __shfl_xor(part[r], d);
            }
            int sgb = s0 + w * 8;
            float mc = -1e30f;
#pragma unroll
            for (int r = 0; r < 8; ++r) {
                part[r] = (sgb + r < vlen) ? part[r] : -1e30f;
                mc = fmaxf(mc, part[r]);
            }
            float e8[8]; float psum = 0.f;
#pragma unroll
            for (int r = 0; r < 8; ++r) {
                e8[r] = (part[r] > -1e29f) ? expf(part[r] - mc) : 0.f;
                psum += e8[r];
            }
            f32x4 ca[4] = {{0,0,0,0},{0,0,0,0},{0,0,0,0},{0,0,0,0}};
#pragma unroll
            for (int r = 0; r < 8; ++r) {
                float p = e8[r];
                const u16* erow = &El[(w * 8 + r) * EL_PITCH];
#pragma unroll
                for (int c = 0; c < 4; ++c) {
                    short4v e4 = *(const short4v*)(erow + c * 256 + lane * 4);
                    ca[c][0] += p * bf2f((u16)e4[0]);
                    ca[c][1] += p * bf2f((u16)e4[1]);
                    ca[c][2] += p * bf2f((u16)e4[2]);
                    ca[c][3] += p * bf2f((u16)e4[3]);
                }
            }
            float* pd = pCtx + (size_t)(t & 3) * (32 * 16 * 1024)
                             + (size_t)(b_at * 16 + ch * 2 + w) * 1024;
#pragma unroll
            for (int c = 0; c < 4; ++c) {
                union { f32x4 v; u64 q[2]; } cu; cu.v = ca[c];
                u64* p = (u64*)(pd + c * 256 + lane * 4);
                stg_u64(p, cu.q[0]);
                stg_u64(p + 1, cu.q[1]);
            }
            if (lane == 0) {
                stg_f32(&pMx[(size_t)(t & 3) * 512 + b_at * 16 + ch * 2 + w], mc);
                stg_f32(&pSm[(size_t)(t & 3) * 512 + b_at * 16 + ch * 2 + w], psum);
            }
        }
        __syncthreads();

        if (t < 63 && tid >= 128) {
            // ---- LSTM elementwise ----
            float G[4];
#pragma unroll
            for (int g = 0; g < 4; ++g) {
                int n = g * 4 + lkk;
                G[g] = red[0][lb][n] + red[1][lb][n] + xgv[g];
            }
            float iS = sigm(G[0]), fS = sigm(G[1]), gT = tanhf(G[2]), oS = sigm(G[3]);
            float cn = fS * creg + iS * gT;
            float hn = oS * tanhf(cn);
            creg = cn;
            u16 h16 = f2bf(hn);
            int sl = (t + 1) & 1;
            stg_f32(&hF[(size_t)sl * (32 * 1024) + lb * 1024 + lkidx], hn);
            stg_u16(&hb[(size_t)sl * (32 * 1024) + lb * 1024 + lkidx], h16);
            hAll[((size_t)t * 32 + lb) * 1024 + lkidx] = h16;
        }

        bar_arrive(slots, (u32)(t + 1), bid, tid);

        // ---- shadow: combine + xg prefetch overlap barrier propagation ----
        if (t >= 2)
            combine16(b_at, ch, t - 2, tid, (t - 1) & 3, pCtx, pMx, pSm, ctxA);
        if (t < 62 && tid >= 128) {
#pragma unroll
            for (int g = 0; g < 4; ++g)
                xgv[g] = bf2f(xg[((size_t)(t + 1) * 32 + lb) * 4096 + g * 1024 + lkidx]);
        }
    }

    bar_wait(slots, 64u, tid);
    combine16(b_at, ch, 62, tid, 3, pCtx, pMx, pSm, ctxA);
    if (bid >= 32 && bid < 64) {
        int b = bid - 32, j = tid * 4;
#pragma unroll
        for (int i = 0; i < 4; ++i)
            out[2064384 + b * 1024 + j + i] = ldg_f32(&hF[(size_t)1 * (32 * 1024) + b * 1024 + j + i]);
    }
    if (tid >= 128)
        out[2064384 + 32768 + lb * 1024 + lkidx] = creg;
}

// ---------------------------------------------------------------------------
__global__ void __launch_bounds__(256)
k_out(const u16* __restrict__ ctxA, const u16* __restrict__ hAll,
      const u16* __restrict__ Wao16, float* __restrict__ out)
{
    const int bid = blockIdx.x, tid = threadIdx.x;
    const int mt = bid & 31, nt = bid >> 5;
    const int wv = tid >> 6, l = tid & 63, lr = l & 15, lq = l >> 4;
    const int r0 = mt * 64 + wv * 16;
    const int n0 = nt * 64;
    int r = r0 + lr;
    int rc = (r < 2016) ? r : 2015;
    const u16* arc = ctxA + (size_t)rc * 1024;
    const u16* arh = hAll + (size_t)rc * 1024;
    const u16* brow = Wao16 + (size_t)(n0 + lr) * 2048;
    f32x4 acc[4] = {{0,0,0,0},{0,0,0,0},{0,0,0,0},{0,0,0,0}};
    for (int k0 = 0; k0 < 2048; k0 += 32) {
        int ko = k0 + lq * 8;
        short8 av = (k0 < 1024) ? *(const short8*)(arc + ko)
                                : *(const short8*)(arh + (ko - 1024));
#pragma unroll
        for (int nf = 0; nf < 4; ++nf) {
            short8 bv = *(const short8*)(brow + (size_t)nf * 16 * 2048 + ko);
            acc[nf] = __builtin_amdgcn_mfma_f32_16x16x32_bf16(av, bv, acc[nf], 0, 0, 0);
        }
    }
#pragma unroll
    for (int nf = 0; nf < 4; ++nf) {
        int n = n0 + nf * 16 + lr;
#pragma unroll
        for (int q = 0; q < 4; ++q) {
            int rr = r0 + lq * 4 + q;
            if (rr < 2016) {
                int t = rr >> 5, b = rr & 31;
                out[(size_t)b * 64512 + t * 1024 + n] = tanhf(acc[nf][q]);
            }
        }
    }
}

// ---------------------------------------------------------------------------
extern "C" void kernel_launch(void* const* d_in, const int* in_sizes, int n_in,
                              void* d_out, int out_size, void* d_ws, size_t ws_size,
                              hipStream_t stream)
{
    (void)in_sizes; (void)n_in; (void)out_size; (void)ws_size;
    const int*   tgt  = (const int*)d_in[0];
    const float* h0   = (const float*)d_in[1];
    const float* c0   = (const float*)d_in[2];
    const float* enc  = (const float*)d_in[3];
    const int*   slen = (const int*)d_in[4];
    const float* emb  = (const float*)d_in[5];
    const float* Wih  = (const float*)d_in[6];
    const float* Whh  = (const float*)d_in[7];
    const float* bih  = (const float*)d_in[8];
    const float* bhh  = (const float*)d_in[9];
    const float* Wai  = (const float*)d_in[10];
    const float* Wao  = (const float*)d_in[11];
    float* out = (float*)d_out;

    char* ws = (char*)d_ws;
    size_t off = 0;
    auto alloc = [&](size_t bytes) -> char* {
        char* p = ws + off; off += (bytes + 255) & ~(size_t)255; return p;
    };
    u16*   Wih16 = (u16*)  alloc(4096UL * 1024 * 2);
    u16*   Wao16 = (u16*)  alloc(1024UL * 2048 * 2);
    u16*   enc16 = (u16*)  alloc(4096UL * 1024 * 2);
    u16*   xrow  = (u16*)  alloc(2016UL * 1024 * 2);
    u16*   WT    = (u16*)  alloc(1024UL * 1024 * 2);
    u16*   xg    = (u16*)  alloc(2016UL * 4096 * 2);
    float* Mf    = (float*)alloc(4096UL * 1024 * 4);
    u16*   hb    = (u16*)  alloc(2UL * 32 * 1024 * 2);
    float* hF    = (float*)alloc(2UL * 32 * 1024 * 4);
    float* cF    = (float*)alloc(32UL * 1024 * 4);
    u16*   hAll  = (u16*)  alloc(2016UL * 1024 * 2);
    u16*   ctxA  = (u16*)  alloc(2016UL * 1024 * 2);
    float* pCtx  = (float*)alloc(4UL * 32 * 16 * 1024 * 4);
    float* pMx   = (float*)alloc(4UL * 512 * 4);
    float* pSm   = (float*)alloc(4UL * 512 * 4);
    u32*   bar   = (u32*)  alloc(2048);

    static int lds_set = 0;
    if (!lds_set) {
        (void)hipFuncSetAttribute((const void*)k_loop,
                                  hipFuncAttributeMaxDynamicSharedMemorySize, DYN_BYTES);
        lds_set = 1;
    }

    hipMemsetAsync(bar, 0, 2048, stream);
    hipLaunchKernelGGL(k_prep, dim3(12544), dim3(256), 0, stream,
                       Wih, Wih16, Wao, Wao16, enc, enc16, tgt, emb, xrow,
                       Wai, WT, h0, c0, cF, hb);
    hipLaunchKernelGGL(k_mm, dim3(3072), dim3(256), 0, stream,
                       xrow, Wih16, bih, bhh, xg, enc16, WT, Mf);

    void* kargs[] = { (void*)&xg, (void*)&Mf, (void*)&ctxA, (void*)&hAll, (void*)&hb,
                      (void*)&hF, (void*)&cF, (void*)&pCtx, (void*)&pMx, (void*)&pSm,
                      (void*)&enc, (void*)&Whh, (void*)&slen, (void*)&out, (void*)&bar };
    hipLaunchCooperativeKernel((const void*)k_loop, dim3(256), dim3(256), kargs, DYN_BYTES, stream);

    hipLaunchKernelGGL(k_out, dim3(512), dim3(256), 0, stream, ctxA, hAll, Wao16, out);
}

// Round 13
// 733.339 us; speedup vs baseline: 1.4156x; 1.0216x over previous
//
#include <hip/hip_runtime.h>

typedef __attribute__((ext_vector_type(4))) float f32x4;
typedef __attribute__((ext_vector_type(4))) int i32x4;
typedef __attribute__((ext_vector_type(8))) short short8;
typedef __attribute__((ext_vector_type(4))) short short4v;
typedef unsigned short u16;
typedef unsigned int u32;
typedef unsigned long long u64;

#define DEV static __device__ __forceinline__

DEV float bf2f(u16 u){ union { unsigned int i; float f; } v; v.i = ((unsigned int)u) << 16; return v.f; }
DEV u16 f2bf(float f){ union { float f; unsigned int i; } v; v.f = f; unsigned int r = v.i + 0x7fffu + ((v.i >> 16) & 1u); return (u16)(r >> 16); }
DEV float sigm(float x){ return 1.f / (1.f + expf(-x)); }

// write-through (agent-coherent) stores
DEV void stg_f32(float* p, float v){ __hip_atomic_store(p, v, __ATOMIC_RELAXED, __HIP_MEMORY_SCOPE_AGENT); }
DEV void stg_u16(u16* p, u16 v){ __hip_atomic_store(p, v, __ATOMIC_RELAXED, __HIP_MEMORY_SCOPE_AGENT); }
DEV void stg_u64(u64* p, u64 v){ __hip_atomic_store(p, v, __ATOMIC_RELAXED, __HIP_MEMORY_SCOPE_AGENT); }
// coherent reads (relaxed, agent scope)
DEV u64 ldg_u64(const u64* p){ return __hip_atomic_load(p, __ATOMIC_RELAXED, __HIP_MEMORY_SCOPE_AGENT); }
DEV float ldg_f32(const float* p){ return __hip_atomic_load(p, __ATOMIC_RELAXED, __HIP_MEMORY_SCOPE_AGENT); }
// cache-bypassing 16B load (issue only; caller does s_waitcnt + sched_barrier)
DEV void ldcc4i(i32x4* d, const void* p){
    asm volatile("global_load_dwordx4 %0, %1, off sc0 sc1" : "=v"(*d) : "v"(p) : "memory");
}
DEV void ldcc4f(f32x4* d, const void* p){
    asm volatile("global_load_dwordx4 %0, %1, off sc0 sc1" : "=v"(*d) : "v"(p) : "memory");
}
DEV short8 as_s8(i32x4 v){ union{ i32x4 i; short8 s; } u; u.i = v; return u.s; }

DEV short8 cvt8(const float* __restrict__ p){
    const f32x4* q = (const f32x4*)p;
    f32x4 lo = q[0], hi = q[1];
    short8 r;
    r[0]=(short)f2bf(lo[0]); r[1]=(short)f2bf(lo[1]); r[2]=(short)f2bf(lo[2]); r[3]=(short)f2bf(lo[3]);
    r[4]=(short)f2bf(hi[0]); r[5]=(short)f2bf(hi[1]); r[6]=(short)f2bf(hi[2]); r[7]=(short)f2bf(hi[3]);
    return r;
}

// ---------------------------------------------------------------------------
// Distributed grid barrier (no L2 invalidation; shared data read sc0/sc1).
// ---------------------------------------------------------------------------
DEV void bar_arrive(u32* __restrict__ slots, u32 n, int bid, int tid)
{
    asm volatile("s_waitcnt vmcnt(0)" ::: "memory");
    __syncthreads();
    if (tid == 0)
        __hip_atomic_store(&slots[bid], n, __ATOMIC_RELAXED, __HIP_MEMORY_SCOPE_AGENT);
}

DEV void bar_wait(u32* __restrict__ slots, u32 n, int tid)
{
    if (tid < 64) {
        for (;;) {
            u32 v0 = __hip_atomic_load(&slots[tid*4+0], __ATOMIC_RELAXED, __HIP_MEMORY_SCOPE_AGENT);
            u32 v1 = __hip_atomic_load(&slots[tid*4+1], __ATOMIC_RELAXED, __HIP_MEMORY_SCOPE_AGENT);
            u32 v2 = __hip_atomic_load(&slots[tid*4+2], __ATOMIC_RELAXED, __HIP_MEMORY_SCOPE_AGENT);
            u32 v3 = __hip_atomic_load(&slots[tid*4+3], __ATOMIC_RELAXED, __HIP_MEMORY_SCOPE_AGENT);
            bool ok = (v0 >= n) && (v1 >= n) && (v2 >= n) && (v3 >= n);
            if (__all(ok)) break;
            __builtin_amdgcn_s_sleep(1);
        }
    }
    __syncthreads();
}

// ---------------------------------------------------------------------------
// k_prep: fused one-shot prep (unchanged, round-7 known-good).
// ---------------------------------------------------------------------------
__global__ void __launch_bounds__(256)
k_prep(const float* __restrict__ Wih, u16* __restrict__ Wih16,
       const float* __restrict__ Wao, u16* __restrict__ Wao16,
       const float* __restrict__ enc, u16* __restrict__ enc16,
       const int* __restrict__ tgt, const float* __restrict__ emb, u16* __restrict__ xrow,
       const float* __restrict__ Wai, u16* __restrict__ WT,
       const float* __restrict__ h0, const float* __restrict__ c0,
       float* __restrict__ cF, u16* __restrict__ hb)
{
    const int bid = blockIdx.x, tid = threadIdx.x;
    __shared__ u16 tl[64][65];
    if (bid < 10240) {
        const float* src; u16* dst; int i;
        if (bid < 4096)      { src = Wih; dst = Wih16; i = bid * 1024 + tid * 4; }
        else if (bid < 6144) { src = Wao; dst = Wao16; i = (bid - 4096) * 1024 + tid * 4; }
        else                 { src = enc; dst = enc16; i = (bid - 6144) * 1024 + tid * 4; }
        f32x4 v = *(const f32x4*)(src + i);
        short4v o;
        o[0]=(short)f2bf(v[0]); o[1]=(short)f2bf(v[1]);
        o[2]=(short)f2bf(v[2]); o[3]=(short)f2bf(v[3]);
        *(short4v*)(dst + i) = o;
    } else if (bid < 12256) {
        int r = bid - 10240;
        int t = r >> 5, b = r & 31;
        const float* src = emb + (size_t)tgt[b * 64 + t] * 1024;
        int j = tid * 4;
        f32x4 v = *(const f32x4*)(src + j);
        short4v o;
        o[0]=(short)f2bf(v[0]); o[1]=(short)f2bf(v[1]);
        o[2]=(short)f2bf(v[2]); o[3]=(short)f2bf(v[3]);
        *(short4v*)(xrow + (size_t)r * 1024 + j) = o;
    } else if (bid < 12512) {
        int tb = bid - 12256;
        int ti = tb >> 4, tj = tb & 15;
        int rr = tid >> 2, cc = (tid & 3) * 16;
        for (int i = 0; i < 16; ++i)
            tl[rr][cc + i] = f2bf(Wai[(size_t)(ti * 64 + rr) * 1024 + tj * 64 + cc + i]);
        __syncthreads();
        for (int i = 0; i < 16; ++i)
            WT[(size_t)(tj * 64 + rr) * 1024 + ti * 64 + cc + i] = tl[cc + i][rr];
    } else {
        int b = bid - 12512;
        int j = tid * 4;
        for (int i = 0; i < 4; ++i) {
            int k = j + i;
            float hv = (k < 512) ? h0[(size_t)b * 512 + k] : h0[(size_t)(32 + b) * 512 + (k - 512)];
            float cv = (k < 512) ? c0[(size_t)b * 512 + k] : c0[(size_t)(32 + b) * 512 + (k - 512)];
            cF[b * 1024 + k] = cv;
            hb[b * 1024 + k] = f2bf(hv);
        }
    }
}

// ---------------------------------------------------------------------------
// k_mm: fused xg-GEMM [0,2048) and M-GEMM [2048,3072).
// NEW: depth-4 register prefetch pipeline (aq[4], bq[4][4]) — hides global
// load latency behind 16 MFMAs; full unroll keeps indices compile-time.
// ---------------------------------------------------------------------------
__global__ void __launch_bounds__(256)
k_mm(const u16* __restrict__ xrow, const u16* __restrict__ Wih16,
     const float* __restrict__ bih, const float* __restrict__ bhh, u16* __restrict__ xg,
     const u16* __restrict__ enc16, const u16* __restrict__ WT, float* __restrict__ Mf)
{
    const int tid = threadIdx.x;
    const int wv = tid >> 6, l = tid & 63, lr = l & 15, lq = l >> 4;
    if (blockIdx.x < 2048) {
        const int bid = blockIdx.x;
        const int mt = bid & 31, nt = bid >> 5;
        const int r0 = mt * 64 + wv * 16;
        const int n0 = nt * 64;
        int r = r0 + lr;
        int rc = (r < 2016) ? r : 2015;
        const u16* arow = xrow + (size_t)rc * 1024 + lq * 8;
        const u16* brow = Wih16 + (size_t)(n0 + lr) * 1024 + lq * 8;
        short8 aq[4]; short8 bq[4][4];
#pragma unroll
        for (int s = 0; s < 4; ++s) {
            aq[s] = *(const short8*)(arow + s * 32);
#pragma unroll
            for (int nf = 0; nf < 4; ++nf)
                bq[s][nf] = *(const short8*)(brow + (size_t)nf * 16 * 1024 + s * 32);
        }
        f32x4 acc[4] = {{0,0,0,0},{0,0,0,0},{0,0,0,0},{0,0,0,0}};
#pragma unroll
        for (int k = 0; k < 32; ++k) {
            short8 av = aq[k & 3];
            short8 bv0 = bq[k & 3][0], bv1 = bq[k & 3][1], bv2 = bq[k & 3][2], bv3 = bq[k & 3][3];
            if (k + 4 < 32) {
                int ko = (k + 4) * 32;
                aq[k & 3] = *(const short8*)(arow + ko);
#pragma unroll
                for (int nf = 0; nf < 4; ++nf)
                    bq[k & 3][nf] = *(const short8*)(brow + (size_t)nf * 16 * 1024 + ko);
            }
            acc[0] = __builtin_amdgcn_mfma_f32_16x16x32_bf16(av, bv0, acc[0], 0, 0, 0);
            acc[1] = __builtin_amdgcn_mfma_f32_16x16x32_bf16(av, bv1, acc[1], 0, 0, 0);
            acc[2] = __builtin_amdgcn_mfma_f32_16x16x32_bf16(av, bv2, acc[2], 0, 0, 0);
            acc[3] = __builtin_amdgcn_mfma_f32_16x16x32_bf16(av, bv3, acc[3], 0, 0, 0);
        }
#pragma unroll
        for (int nf = 0; nf < 4; ++nf) {
            int n = n0 + nf * 16 + lr;
            float bias = bih[n] + bhh[n];
#pragma unroll
            for (int q = 0; q < 4; ++q) {
                int rr = r0 + lq * 4 + q;
                if (rr < 2016) xg[(size_t)rr * 4096 + n] = f2bf(acc[nf][q] + bias);
            }
        }
    } else {
        const int bid = blockIdx.x - 2048;
        const int mt = bid & 63, nt = bid >> 6;
        const int r0 = mt * 64 + wv * 16;
        const int n0 = nt * 64;
        const u16* arow = enc16 + (size_t)(r0 + lr) * 1024 + lq * 8;
        const u16* brow = WT + (size_t)(n0 + lr) * 1024 + lq * 8;
        short8 aq[4]; short8 bq[4][4];
#pragma unroll
        for (int s = 0; s < 4; ++s) {
            aq[s] = *(const short8*)(arow + s * 32);
#pragma unroll
            for (int nf = 0; nf < 4; ++nf)
                bq[s][nf] = *(const short8*)(brow + (size_t)nf * 16 * 1024 + s * 32);
        }
        f32x4 acc[4] = {{0,0,0,0},{0,0,0,0},{0,0,0,0},{0,0,0,0}};
#pragma unroll
        for (int k = 0; k < 32; ++k) {
            short8 av = aq[k & 3];
            short8 bv0 = bq[k & 3][0], bv1 = bq[k & 3][1], bv2 = bq[k & 3][2], bv3 = bq[k & 3][3];
            if (k + 4 < 32) {
                int ko = (k + 4) * 32;
                aq[k & 3] = *(const short8*)(arow + ko);
#pragma unroll
                for (int nf = 0; nf < 4; ++nf)
                    bq[k & 3][nf] = *(const short8*)(brow + (size_t)nf * 16 * 1024 + ko);
            }
            acc[0] = __builtin_amdgcn_mfma_f32_16x16x32_bf16(av, bv0, acc[0], 0, 0, 0);
            acc[1] = __builtin_amdgcn_mfma_f32_16x16x32_bf16(av, bv1, acc[1], 0, 0, 0);
            acc[2] = __builtin_amdgcn_mfma_f32_16x16x32_bf16(av, bv2, acc[2], 0, 0, 0);
            acc[3] = __builtin_amdgcn_mfma_f32_16x16x32_bf16(av, bv3, acc[3], 0, 0, 0);
        }
#pragma unroll
        for (int nf = 0; nf < 4; ++nf) {
            int n = n0 + nf * 16 + lr;
#pragma unroll
            for (int q = 0; q < 4; ++q)
                Mf[(size_t)(r0 + lq * 4 + q) * 1024 + n] = acc[nf][q];
        }
    }
}

// ---------------------------------------------------------------------------
// combine 16 half-chunk partials -> ctxA[tstore] (tid<32)
// ---------------------------------------------------------------------------
DEV void combine16(int b, int ch, int tstore, int tid, int slot,
                   const float* __restrict__ pCtx, const float* __restrict__ pMx,
                   const float* __restrict__ pSm, u16* __restrict__ ctxA)
{
    if (tid >= 32) return;
    const float* mx = pMx + (size_t)slot * 512 + b * 16;
    const float* sm = pSm + (size_t)slot * 512 + b * 16;
    const float* pc = pCtx + (size_t)slot * (32 * 16 * 1024) + (size_t)b * 16 * 1024;
    float m16[16], s16[16];
#pragma unroll
    for (int c = 0; c < 16; ++c) { m16[c] = ldg_f32(mx + c); s16[c] = ldg_f32(sm + c); }
    float gm = -1e30f;
#pragma unroll
    for (int c = 0; c < 16; ++c) gm = fmaxf(gm, m16[c]);
    float wsum = 0.f, e[16];
#pragma unroll
    for (int c = 0; c < 16; ++c) { e[c] = expf(m16[c] - gm); wsum += s16[c] * e[c]; }
    float inv = 1.f / wsum;
    int j = ch * 128 + tid * 4;
    f32x4 a = {0.f, 0.f, 0.f, 0.f};
#pragma unroll
    for (int c = 0; c < 16; ++c) {
        union { u64 q[2]; f32x4 v; } u;
        const u64* p = (const u64*)(pc + (size_t)c * 1024 + j);
        u.q[0] = ldg_u64(p); u.q[1] = ldg_u64(p + 1);
        float s = e[c] * inv;
        a[0] += u.v[0] * s; a[1] += u.v[1] * s; a[2] += u.v[2] * s; a[3] += u.v[3] * s;
    }
    short4v o4;
    o4[0] = (short)f2bf(a[0]); o4[1] = (short)f2bf(a[1]);
    o4[2] = (short)f2bf(a[2]); o4[3] = (short)f2bf(a[3]);
    *(short4v*)(ctxA + ((size_t)tstore * 32 + b) * 1024 + j) = o4;
}

// ---------------------------------------------------------------------------
// k_loop: wave-specialized persistent kernel (round-7 known-good, untouched).
// ---------------------------------------------------------------------------
#define ML_PITCH 1028
#define EL_PITCH 1032
#define ML_BYTES (16 * ML_PITCH * 4)
#define EL_BYTES (16 * EL_PITCH * 2)
#define DYN_BYTES (ML_BYTES + EL_BYTES)

__global__ void __launch_bounds__(256, 1)
k_loop(const u16* __restrict__ xg, const float* __restrict__ Mf,
       u16* __restrict__ ctxA, u16* __restrict__ hAll,
       u16* __restrict__ hb, float* __restrict__ hF, float* __restrict__ cF,
       float* __restrict__ pCtx, float* __restrict__ pMx, float* __restrict__ pSm,
       const float* __restrict__ enc, const float* __restrict__ Whh,
       const int* __restrict__ slen, float* __restrict__ out, u32* __restrict__ bar)
{
    const int bid = blockIdx.x, tid = threadIdx.x;
    const int wv = tid >> 6, l = tid & 63, lr = l & 15, lq = l >> 4;
    u32* slots = bar;

    extern __shared__ char smem[];
    float* Ml = (float*)smem;                 // [16][ML_PITCH]
    u16*   El = (u16*)(smem + ML_BYTES);      // [16][EL_PITCH]

    __shared__ float red[2][32][16];

    const int b_at = bid >> 3, ch = bid & 7, s0 = ch * 16;

    // ---- prologue ----
    short8 breg[16];
    if (wv < 2) {
        const float* wsrc = Whh + ((size_t)((lr >> 2) * 1024 + bid * 4 + (lr & 3))) * 1024
                                + wv * 512 + lq * 8;
#pragma unroll
        for (int ks = 0; ks < 16; ++ks)
            breg[ks] = cvt8(wsrc + ks * 32);
    }
    {   // M slice (fp32)
        int row = tid >> 4;
        const float* src = Mf + (size_t)(b_at * 128 + s0 + row) * 1024;
        float* dst = &Ml[row * ML_PITCH];
#pragma unroll
        for (int i = 0; i < 16; ++i) {
            int c = (tid & 15) * 4 + i * 64;
            *(f32x4*)(dst + c) = *(const f32x4*)(src + c);
        }
    }
    {   // enc slice (bf16)
        int row = tid >> 4;
        const float* src = enc + (size_t)(b_at * 128 + s0 + row) * 1024;
        u16* dst = &El[row * EL_PITCH];
#pragma unroll
        for (int i = 0; i < 16; ++i) {
            int c = (tid & 15) * 4 + i * 64;
            f32x4 v = *(const f32x4*)(src + c);
            short4v o;
            o[0]=(short)f2bf(v[0]); o[1]=(short)f2bf(v[1]);
            o[2]=(short)f2bf(v[2]); o[3]=(short)f2bf(v[3]);
            *(short4v*)(dst + c) = o;
        }
    }

    const int lb = tid & 31, lkk = (tid >> 5) - 4;
    const int lkidx = bid * 4 + lkk;
    float creg = 0.f;
    float xgv[4] = {0,0,0,0};
    if (tid >= 128) {
        creg = cF[lb * 1024 + lkidx];
#pragma unroll
        for (int g = 0; g < 4; ++g)
            xgv[g] = bf2f(xg[((size_t)lb) * 4096 + g * 1024 + lkidx]);   // t=0
    }
    int vlen = slen[b_at]; if (vlen < 1) vlen = 1;
    __syncthreads();

    for (int t = 0; t < 64; ++t) {
        if (t >= 1) bar_wait(slots, (u32)t, tid);

        if (t < 63 && wv < 2) {
            const u16* hrd = hb + (size_t)(t & 1) * (32 * 1024);
            const u16* p0 = hrd + lr * 1024 + wv * 512 + lq * 8;
            const u16* p1 = p0 + 16 * 1024;
            i32x4 a0b[16], a1b[16];
#pragma unroll
            for (int ks = 0; ks < 16; ++ks) {
                ldcc4i(&a0b[ks], p0 + ks * 32);
                ldcc4i(&a1b[ks], p1 + ks * 32);
            }
            f32x4 acc0 = {0,0,0,0}, acc1 = {0,0,0,0};
#pragma unroll
            for (int ks = 0; ks < 16; ++ks) {
                asm volatile("s_waitcnt vmcnt(%0)" :: "i"(30 - 2 * ks) : "memory");
                __builtin_amdgcn_sched_barrier(0);
                acc0 = __builtin_amdgcn_mfma_f32_16x16x32_bf16(as_s8(a0b[ks]), breg[ks], acc0, 0, 0, 0);
                acc1 = __builtin_amdgcn_mfma_f32_16x16x32_bf16(as_s8(a1b[ks]), breg[ks], acc1, 0, 0, 0);
            }
#pragma unroll
            for (int q = 0; q < 4; ++q) {
                red[wv][lq * 4 + q][lr] = acc0[q];
                red[wv][16 + lq * 4 + q][lr] = acc1[q];
            }
        }

        if (t >= 1 && wv >= 2) {
            const int w = wv - 2;
            const int lane = l;
            const float* hrow = hF + (size_t)(t & 1) * (32 * 1024) + b_at * 1024;
            f32x4 hreg[4];
            ldcc4f(&hreg[0], hrow + 0 * 256 + lane * 4);
            ldcc4f(&hreg[1], hrow + 1 * 256 + lane * 4);
            ldcc4f(&hreg[2], hrow + 2 * 256 + lane * 4);
            ldcc4f(&hreg[3], hrow + 3 * 256 + lane * 4);
            asm volatile("s_waitcnt vmcnt(0)" ::: "memory");
            __builtin_amdgcn_sched_barrier(0);
            float part[8];
#pragma unroll
            for (int r = 0; r < 8; ++r) {
                const float* mrow = &Ml[(w * 8 + r) * ML_PITCH];
                float s = 0.f;
#pragma unroll
                for (int c = 0; c < 4; ++c) {
                    f32x4 m4 = *(const f32x4*)(mrow + c * 256 + lane * 4);
                    s += m4[0]*hreg[c][0] + m4[1]*hreg[c][1] + m4[2]*hreg[c][2] + m4[3]*hreg[c][3];
                }
                part[r] = s;
            }
#pragma unroll
            for (int d = 1; d < 64; d <<= 1) {
#pragma unroll
                for (int r = 0; r < 8; ++r) part[r] += __shfl_xor(part[r], d);
            }
            int sgb = s0 + w * 8;
            float mc = -1e30f;
#pragma unroll
            for (int r = 0; r < 8; ++r) {
                part[r] = (sgb + r < vlen) ? part[r] : -1e30f;
                mc = fmaxf(mc, part[r]);
            }
            float e8[8]; float psum = 0.f;
#pragma unroll
            for (int r = 0; r < 8; ++r) {
                e8[r] = (part[r] > -1e29f) ? expf(part[r] - mc) : 0.f;
                psum += e8[r];
            }
            f32x4 ca[4] = {{0,0,0,0},{0,0,0,0},{0,0,0,0},{0,0,0,0}};
#pragma unroll
            for (int r = 0; r < 8; ++r) {
                float p = e8[r];
                const u16* erow = &El[(w * 8 + r) * EL_PITCH];
#pragma unroll
                for (int c = 0; c < 4; ++c) {
                    short4v e4 = *(const short4v*)(erow + c * 256 + lane * 4);
                    ca[c][0] += p * bf2f((u16)e4[0]);
                    ca[c][1] += p * bf2f((u16)e4[1]);
                    ca[c][2] += p * bf2f((u16)e4[2]);
                    ca[c][3] += p * bf2f((u16)e4[3]);
                }
            }
            float* pd = pCtx + (size_t)(t & 3) * (32 * 16 * 1024)
                             + (size_t)(b_at * 16 + ch * 2 + w) * 1024;
#pragma unroll
            for (int c = 0; c < 4; ++c) {
                union { f32x4 v; u64 q[2]; } cu; cu.v = ca[c];
                u64* p = (u64*)(pd + c * 256 + lane * 4);
                stg_u64(p, cu.q[0]);
                stg_u64(p + 1, cu.q[1]);
            }
            if (lane == 0) {
                stg_f32(&pMx[(size_t)(t & 3) * 512 + b_at * 16 + ch * 2 + w], mc);
                stg_f32(&pSm[(size_t)(t & 3) * 512 + b_at * 16 + ch * 2 + w], psum);
            }
        }
        __syncthreads();

        if (t < 63 && tid >= 128) {
            float G[4];
#pragma unroll
            for (int g = 0; g < 4; ++g) {
                int n = g * 4 + lkk;
                G[g] = red[0][lb][n] + red[1][lb][n] + xgv[g];
            }
            float iS = sigm(G[0]), fS = sigm(G[1]), gT = tanhf(G[2]), oS = sigm(G[3]);
            float cn = fS * creg + iS * gT;
            float hn = oS * tanhf(cn);
            creg = cn;
            u16 h16 = f2bf(hn);
            int sl = (t + 1) & 1;
            stg_f32(&hF[(size_t)sl * (32 * 1024) + lb * 1024 + lkidx], hn);
            stg_u16(&hb[(size_t)sl * (32 * 1024) + lb * 1024 + lkidx], h16);
            hAll[((size_t)t * 32 + lb) * 1024 + lkidx] = h16;
        }

        bar_arrive(slots, (u32)(t + 1), bid, tid);

        if (t >= 2)
            combine16(b_at, ch, t - 2, tid, (t - 1) & 3, pCtx, pMx, pSm, ctxA);
        if (t < 62 && tid >= 128) {
#pragma unroll
            for (int g = 0; g < 4; ++g)
                xgv[g] = bf2f(xg[((size_t)(t + 1) * 32 + lb) * 4096 + g * 1024 + lkidx]);
        }
    }

    bar_wait(slots, 64u, tid);
    combine16(b_at, ch, 62, tid, 3, pCtx, pMx, pSm, ctxA);
    if (bid >= 32 && bid < 64) {
        int b = bid - 32, j = tid * 4;
#pragma unroll
        for (int i = 0; i < 4; ++i)
            out[2064384 + b * 1024 + j + i] = ldg_f32(&hF[(size_t)1 * (32 * 1024) + b * 1024 + j + i]);
    }
    if (tid >= 128)
        out[2064384 + 32768 + lb * 1024 + lkidx] = creg;
}

// ---------------------------------------------------------------------------
// k_out: output GEMM, NEW depth-4 register prefetch pipeline.
// ---------------------------------------------------------------------------
__global__ void __launch_bounds__(256)
k_out(const u16* __restrict__ ctxA, const u16* __restrict__ hAll,
      const u16* __restrict__ Wao16, float* __restrict__ out)
{
    const int bid = blockIdx.x, tid = threadIdx.x;
    const int mt = bid & 31, nt = bid >> 5;
    const int wv = tid >> 6, l = tid & 63, lr = l & 15, lq = l >> 4;
    const int r0 = mt * 64 + wv * 16;
    const int n0 = nt * 64;
    int r = r0 + lr;
    int rc = (r < 2016) ? r : 2015;
    const u16* arc = ctxA + (size_t)rc * 1024 + lq * 8;
    const u16* arh = hAll + (size_t)rc * 1024 + lq * 8;
    const u16* brow = Wao16 + (size_t)(n0 + lr) * 2048 + lq * 8;
    short8 aq[4]; short8 bq[4][4];
#pragma unroll
    for (int s = 0; s < 4; ++s) {
        aq[s] = *(const short8*)(arc + s * 32);
#pragma unroll
        for (int nf = 0; nf < 4; ++nf)
            bq[s][nf] = *(const short8*)(brow + (size_t)nf * 16 * 2048 + s * 32);
    }
    f32x4 acc[4] = {{0,0,0,0},{0,0,0,0},{0,0,0,0},{0,0,0,0}};
#pragma unroll
    for (int k = 0; k < 64; ++k) {
        short8 av = aq[k & 3];
        short8 bv0 = bq[k & 3][0], bv1 = bq[k & 3][1], bv2 = bq[k & 3][2], bv3 = bq[k & 3][3];
        if (k + 4 < 64) {
            int ko = (k + 4) * 32;
            aq[k & 3] = (ko < 1024) ? *(const short8*)(arc + ko)
                                    : *(const short8*)(arh + (ko - 1024));
#pragma unroll
            for (int nf = 0; nf < 4; ++nf)
                bq[k & 3][nf] = *(const short8*)(brow + (size_t)nf * 16 * 2048 + ko);
        }
        acc[0] = __builtin_amdgcn_mfma_f32_16x16x32_bf16(av, bv0, acc[0], 0, 0, 0);
        acc[1] = __builtin_amdgcn_mfma_f32_16x16x32_bf16(av, bv1, acc[1], 0, 0, 0);
        acc[2] = __builtin_amdgcn_mfma_f32_16x16x32_bf16(av, bv2, acc[2], 0, 0, 0);
        acc[3] = __builtin_amdgcn_mfma_f32_16x16x32_bf16(av, bv3, acc[3], 0, 0, 0);
    }
#pragma unroll
    for (int nf = 0; nf < 4; ++nf) {
        int n = n0 + nf * 16 + lr;
#pragma unroll
        for (int q = 0; q < 4; ++q) {
            int rr = r0 + lq * 4 + q;
            if (rr < 2016) {
                int t = rr >> 5, b = rr & 31;
                out[(size_t)b * 64512 + t * 1024 + n] = tanhf(acc[nf][q]);
            }
        }
    }
}

// ---------------------------------------------------------------------------
extern "C" void kernel_launch(void* const* d_in, const int* in_sizes, int n_in,
                              void* d_out, int out_size, void* d_ws, size_t ws_size,
                              hipStream_t stream)
{
    (void)in_sizes; (void)n_in; (void)out_size; (void)ws_size;
    const int*   tgt  = (const int*)d_in[0];
    const float* h0   = (const float*)d_in[1];
    const float* c0   = (const float*)d_in[2];
    const float* enc  = (const float*)d_in[3];
    const int*   slen = (const int*)d_in[4];
    const float* emb  = (const float*)d_in[5];
    const float* Wih  = (const float*)d_in[6];
    const float* Whh  = (const float*)d_in[7];
    const float* bih  = (const float*)d_in[8];
    const float* bhh  = (const float*)d_in[9];
    const float* Wai  = (const float*)d_in[10];
    const float* Wao  = (const float*)d_in[11];
    float* out = (float*)d_out;

    char* ws = (char*)d_ws;
    size_t off = 0;
    auto alloc = [&](size_t bytes) -> char* {
        char* p = ws + off; off += (bytes + 255) & ~(size_t)255; return p;
    };
    u16*   Wih16 = (u16*)  alloc(4096UL * 1024 * 2);
    u16*   Wao16 = (u16*)  alloc(1024UL * 2048 * 2);
    u16*   enc16 = (u16*)  alloc(4096UL * 1024 * 2);
    u16*   xrow  = (u16*)  alloc(2016UL * 1024 * 2);
    u16*   WT    = (u16*)  alloc(1024UL * 1024 * 2);
    u16*   xg    = (u16*)  alloc(2016UL * 4096 * 2);
    float* Mf    = (float*)alloc(4096UL * 1024 * 4);
    u16*   hb    = (u16*)  alloc(2UL * 32 * 1024 * 2);
    float* hF    = (float*)alloc(2UL * 32 * 1024 * 4);
    float* cF    = (float*)alloc(32UL * 1024 * 4);
    u16*   hAll  = (u16*)  alloc(2016UL * 1024 * 2);
    u16*   ctxA  = (u16*)  alloc(2016UL * 1024 * 2);
    float* pCtx  = (float*)alloc(4UL * 32 * 16 * 1024 * 4);
    float* pMx   = (float*)alloc(4UL * 512 * 4);
    float* pSm   = (float*)alloc(4UL * 512 * 4);
    u32*   bar   = (u32*)  alloc(2048);

    static int lds_set = 0;
    if (!lds_set) {
        (void)hipFuncSetAttribute((const void*)k_loop,
                                  hipFuncAttributeMaxDynamicSharedMemorySize, DYN_BYTES);
        lds_set = 1;
    }

    hipMemsetAsync(bar, 0, 2048, stream);
    hipLaunchKernelGGL(k_prep, dim3(12544), dim3(256), 0, stream,
                       Wih, Wih16, Wao, Wao16, enc, enc16, tgt, emb, xrow,
                       Wai, WT, h0, c0, cF, hb);
    hipLaunchKernelGGL(k_mm, dim3(3072), dim3(256), 0, stream,
                       xrow, Wih16, bih, bhh, xg, enc16, WT, Mf);

    void* kargs[] = { (void*)&xg, (void*)&Mf, (void*)&ctxA, (void*)&hAll, (void*)&hb,
                      (void*)&hF, (void*)&cF, (void*)&pCtx, (void*)&pMx, (void*)&pSm,
                      (void*)&enc, (void*)&Whh, (void*)&slen, (void*)&out, (void*)&bar };
    hipLaunchCooperativeKernel((const void*)k_loop, dim3(256), dim3(256), kargs, DYN_BYTES, stream);

    hipLaunchKernelGGL(k_out, dim3(512), dim3(256), 0, stream, ctxA, hAll, Wao16, out);
}

// Round 14
// 559.478 us; speedup vs baseline: 1.8555x; 1.3108x over previous
//
#include <hip/hip_runtime.h>

typedef __attribute__((ext_vector_type(4))) float f32x4;
typedef __attribute__((ext_vector_type(4))) int i32x4;
typedef __attribute__((ext_vector_type(8))) short short8;
typedef __attribute__((ext_vector_type(4))) short short4v;
typedef unsigned short u16;
typedef unsigned int u32;
typedef unsigned long long u64;

#define DEV static __device__ __forceinline__

DEV float bf2f(u16 u){ union { unsigned int i; float f; } v; v.i = ((unsigned int)u) << 16; return v.f; }
DEV u16 f2bf(float f){ union { float f; unsigned int i; } v; v.f = f; unsigned int r = v.i + 0x7fffu + ((v.i >> 16) & 1u); return (u16)(r >> 16); }
DEV float sigm(float x){ return 1.f / (1.f + expf(-x)); }

// write-through (agent-coherent) stores
DEV void stg_f32(float* p, float v){ __hip_atomic_store(p, v, __ATOMIC_RELAXED, __HIP_MEMORY_SCOPE_AGENT); }
DEV void stg_u16(u16* p, u16 v){ __hip_atomic_store(p, v, __ATOMIC_RELAXED, __HIP_MEMORY_SCOPE_AGENT); }
DEV void stg_u64(u64* p, u64 v){ __hip_atomic_store(p, v, __ATOMIC_RELAXED, __HIP_MEMORY_SCOPE_AGENT); }
// coherent reads (relaxed, agent scope)
DEV u64 ldg_u64(const u64* p){ return __hip_atomic_load(p, __ATOMIC_RELAXED, __HIP_MEMORY_SCOPE_AGENT); }
DEV float ldg_f32(const float* p){ return __hip_atomic_load(p, __ATOMIC_RELAXED, __HIP_MEMORY_SCOPE_AGENT); }
// cache-bypassing 16B load (issue only; caller does s_waitcnt + sched_barrier)
DEV void ldcc4i(i32x4* d, const void* p){
    asm volatile("global_load_dwordx4 %0, %1, off sc0 sc1" : "=v"(*d) : "v"(p) : "memory");
}
DEV void ldcc4f(f32x4* d, const void* p){
    asm volatile("global_load_dwordx4 %0, %1, off sc0 sc1" : "=v"(*d) : "v"(p) : "memory");
}
DEV short8 as_s8(i32x4 v){ union{ i32x4 i; short8 s; } u; u.i = v; return u.s; }

DEV short8 cvt8(const float* __restrict__ p){
    const f32x4* q = (const f32x4*)p;
    f32x4 lo = q[0], hi = q[1];
    short8 r;
    r[0]=(short)f2bf(lo[0]); r[1]=(short)f2bf(lo[1]); r[2]=(short)f2bf(lo[2]); r[3]=(short)f2bf(lo[3]);
    r[4]=(short)f2bf(hi[0]); r[5]=(short)f2bf(hi[1]); r[6]=(short)f2bf(hi[2]); r[7]=(short)f2bf(hi[3]);
    return r;
}

// LDS XOR swizzle (G4): spread 8-row stripes across 16B slots
DEV int swz2k(int row, int colb){ return (row * 2048 + colb) ^ ((row & 7) << 4); }
DEV int swz4k(int row, int colb){ return (row * 4096 + colb) ^ ((row & 7) << 4); }

// ---------------------------------------------------------------------------
// Distributed grid barrier (no L2 invalidation; shared data read sc0/sc1).
// ---------------------------------------------------------------------------
DEV void bar_arrive(u32* __restrict__ slots, u32 n, int bid, int tid)
{
    asm volatile("s_waitcnt vmcnt(0)" ::: "memory");
    __syncthreads();
    if (tid == 0)
        __hip_atomic_store(&slots[bid], n, __ATOMIC_RELAXED, __HIP_MEMORY_SCOPE_AGENT);
}

DEV void bar_wait(u32* __restrict__ slots, u32 n, int tid)
{
    if (tid < 64) {
        for (;;) {
            u32 v0 = __hip_atomic_load(&slots[tid*4+0], __ATOMIC_RELAXED, __HIP_MEMORY_SCOPE_AGENT);
            u32 v1 = __hip_atomic_load(&slots[tid*4+1], __ATOMIC_RELAXED, __HIP_MEMORY_SCOPE_AGENT);
            u32 v2 = __hip_atomic_load(&slots[tid*4+2], __ATOMIC_RELAXED, __HIP_MEMORY_SCOPE_AGENT);
            u32 v3 = __hip_atomic_load(&slots[tid*4+3], __ATOMIC_RELAXED, __HIP_MEMORY_SCOPE_AGENT);
            bool ok = (v0 >= n) && (v1 >= n) && (v2 >= n) && (v3 >= n);
            if (__all(ok)) break;
            __builtin_amdgcn_s_sleep(1);
        }
    }
    __syncthreads();
}

// ---------------------------------------------------------------------------
// k_prep: one-shot prep (trimmed: no Wih/Wao conversion — staged in k_mm/k_out)
//   [0,2016)     gather emb rows -> xrow (bf16)
//   [2016,2272)  transpose W_attn_in -> WT (bf16)
//   [2272,2304)  init cF (fp32), hb buf0 (bf16)
//   [2304,6400)  cvt enc -> enc16
// ---------------------------------------------------------------------------
__global__ void __launch_bounds__(256)
k_prep(const float* __restrict__ enc, u16* __restrict__ enc16,
       const int* __restrict__ tgt, const float* __restrict__ emb, u16* __restrict__ xrow,
       const float* __restrict__ Wai, u16* __restrict__ WT,
       const float* __restrict__ h0, const float* __restrict__ c0,
       float* __restrict__ cF, u16* __restrict__ hb)
{
    const int bid = blockIdx.x, tid = threadIdx.x;
    __shared__ u16 tl[64][65];
    if (bid < 2016) {
        int r = bid;
        int t = r >> 5, b = r & 31;
        const float* src = emb + (size_t)tgt[b * 64 + t] * 1024;
        int j = tid * 4;
        f32x4 v = *(const f32x4*)(src + j);
        short4v o;
        o[0]=(short)f2bf(v[0]); o[1]=(short)f2bf(v[1]);
        o[2]=(short)f2bf(v[2]); o[3]=(short)f2bf(v[3]);
        *(short4v*)(xrow + (size_t)r * 1024 + j) = o;
    } else if (bid < 2272) {
        int tb = bid - 2016;
        int ti = tb >> 4, tj = tb & 15;
        int rr = tid >> 2, cc = (tid & 3) * 16;
        for (int i = 0; i < 16; ++i)
            tl[rr][cc + i] = f2bf(Wai[(size_t)(ti * 64 + rr) * 1024 + tj * 64 + cc + i]);
        __syncthreads();
        for (int i = 0; i < 16; ++i)
            WT[(size_t)(tj * 64 + rr) * 1024 + ti * 64 + cc + i] = tl[cc + i][rr];
    } else if (bid < 2304) {
        int b = bid - 2272;
        int j = tid * 4;
        for (int i = 0; i < 4; ++i) {
            int k = j + i;
            float hv = (k < 512) ? h0[(size_t)b * 512 + k] : h0[(size_t)(32 + b) * 512 + (k - 512)];
            float cv = (k < 512) ? c0[(size_t)b * 512 + k] : c0[(size_t)(32 + b) * 512 + (k - 512)];
            cF[b * 1024 + k] = cv;
            hb[b * 1024 + k] = f2bf(hv);
        }
    } else {
        size_t i = (size_t)(bid - 2304) * 1024 + tid * 4;
        f32x4 v = *(const f32x4*)(enc + i);
        short4v o;
        o[0]=(short)f2bf(v[0]); o[1]=(short)f2bf(v[1]);
        o[2]=(short)f2bf(v[2]); o[3]=(short)f2bf(v[3]);
        *(short4v*)(enc16 + i) = o;
    }
}

// ---------------------------------------------------------------------------
// k_mm: xg-GEMM [0,512) (tile 256x64) and M-GEMM [512,768) (tile 256x64).
// B-panel (64 rows x 1024 K, bf16) LDS-resident, XOR-swizzled. 512 thr, 8 waves.
// ---------------------------------------------------------------------------
__global__ void __launch_bounds__(512, 1)
k_mm(const u16* __restrict__ xrow, const float* __restrict__ Wih,
     const float* __restrict__ bih, const float* __restrict__ bhh, u16* __restrict__ xg,
     const u16* __restrict__ enc16, const u16* __restrict__ WT, float* __restrict__ Mf)
{
    extern __shared__ char Bl[];
    const int tid = threadIdx.x;
    const int wv = tid >> 6, l = tid & 63, lr = l & 15, lq = l >> 4;
    const int bx = blockIdx.x;
    const bool isXG = bx < 512;
    int mt, nt;
    const u16* Asrc;
    if (isXG) { mt = bx & 7;          nt = bx >> 3; Asrc = xrow;  }
    else      { int mb = bx - 512; mt = mb & 15; nt = mb >> 4; Asrc = enc16; }

    // ---- stage B panel into LDS (swizzled) ----
    if (isXG) {
        for (int u = tid; u < 8192; u += 512) {
            int row = u >> 7, c8 = (u & 127) * 8;
            *(short8*)(Bl + swz2k(row, c8 * 2)) = cvt8(Wih + (size_t)(nt * 64 + row) * 1024 + c8);
        }
    } else {
        for (int u = tid; u < 8192; u += 512) {
            int row = u >> 7, c8 = (u & 127) * 8;
            *(short8*)(Bl + swz2k(row, c8 * 2)) = *(const short8*)(WT + (size_t)(nt * 64 + row) * 1024 + c8);
        }
    }
    __syncthreads();

    const int r0 = mt * 256 + wv * 32;
    int rA0 = r0 + lr, rA1 = r0 + 16 + lr;
    if (isXG) { if (rA0 > 2015) rA0 = 2015; if (rA1 > 2015) rA1 = 2015; }
    const u16* a0 = Asrc + (size_t)rA0 * 1024 + lq * 8;
    const u16* a1 = Asrc + (size_t)rA1 * 1024 + lq * 8;
    short8 aq0[4], aq1[4];
#pragma unroll
    for (int d = 0; d < 4; ++d) {
        aq0[d] = *(const short8*)(a0 + d * 32);
        aq1[d] = *(const short8*)(a1 + d * 32);
    }
    f32x4 acc[2][4];
#pragma unroll
    for (int rg = 0; rg < 2; ++rg)
#pragma unroll
        for (int nf = 0; nf < 4; ++nf) acc[rg][nf] = (f32x4){0.f, 0.f, 0.f, 0.f};

#pragma unroll
    for (int k = 0; k < 32; ++k) {
        short8 av0 = aq0[k & 3], av1 = aq1[k & 3];
        if (k + 4 < 32) {
            aq0[k & 3] = *(const short8*)(a0 + (k + 4) * 32);
            aq1[k & 3] = *(const short8*)(a1 + (k + 4) * 32);
        }
#pragma unroll
        for (int nf = 0; nf < 4; ++nf) {
            short8 bv = *(const short8*)(Bl + swz2k(nf * 16 + lr, (lq * 8 + k * 32) * 2));
            acc[0][nf] = __builtin_amdgcn_mfma_f32_16x16x32_bf16(av0, bv, acc[0][nf], 0, 0, 0);
            acc[1][nf] = __builtin_amdgcn_mfma_f32_16x16x32_bf16(av1, bv, acc[1][nf], 0, 0, 0);
        }
    }

    if (isXG) {
#pragma unroll
        for (int rg = 0; rg < 2; ++rg)
#pragma unroll
        for (int nf = 0; nf < 4; ++nf) {
            int n = nt * 64 + nf * 16 + lr;
            float bias = bih[n] + bhh[n];
#pragma unroll
            for (int q = 0; q < 4; ++q) {
                int rr = r0 + rg * 16 + lq * 4 + q;
                if (rr < 2016) xg[(size_t)rr * 4096 + n] = f2bf(acc[rg][nf][q] + bias);
            }
        }
    } else {
#pragma unroll
        for (int rg = 0; rg < 2; ++rg)
#pragma unroll
        for (int nf = 0; nf < 4; ++nf) {
            int n = nt * 64 + nf * 16 + lr;
#pragma unroll
            for (int q = 0; q < 4; ++q)
                Mf[(size_t)(r0 + rg * 16 + lq * 4 + q) * 1024 + n] = acc[rg][nf][q];
        }
    }
}

// ---------------------------------------------------------------------------
// combine 16 half-chunk partials -> ctxA[tstore] (tid<32)
// ---------------------------------------------------------------------------
DEV void combine16(int b, int ch, int tstore, int tid, int slot,
                   const float* __restrict__ pCtx, const float* __restrict__ pMx,
                   const float* __restrict__ pSm, u16* __restrict__ ctxA)
{
    if (tid >= 32) return;
    const float* mx = pMx + (size_t)slot * 512 + b * 16;
    const float* sm = pSm + (size_t)slot * 512 + b * 16;
    const float* pc = pCtx + (size_t)slot * (32 * 16 * 1024) + (size_t)b * 16 * 1024;
    float m16[16], s16[16];
#pragma unroll
    for (int c = 0; c < 16; ++c) { m16[c] = ldg_f32(mx + c); s16[c] = ldg_f32(sm + c); }
    float gm = -1e30f;
#pragma unroll
    for (int c = 0; c < 16; ++c) gm = fmaxf(gm, m16[c]);
    float wsum = 0.f, e[16];
#pragma unroll
    for (int c = 0; c < 16; ++c) { e[c] = expf(m16[c] - gm); wsum += s16[c] * e[c]; }
    float inv = 1.f / wsum;
    int j = ch * 128 + tid * 4;
    f32x4 a = {0.f, 0.f, 0.f, 0.f};
#pragma unroll
    for (int c = 0; c < 16; ++c) {
        union { u64 q[2]; f32x4 v; } u;
        const u64* p = (const u64*)(pc + (size_t)c * 1024 + j);
        u.q[0] = ldg_u64(p); u.q[1] = ldg_u64(p + 1);
        float s = e[c] * inv;
        a[0] += u.v[0] * s; a[1] += u.v[1] * s; a[2] += u.v[2] * s; a[3] += u.v[3] * s;
    }
    short4v o4;
    o4[0] = (short)f2bf(a[0]); o4[1] = (short)f2bf(a[1]);
    o4[2] = (short)f2bf(a[2]); o4[3] = (short)f2bf(a[3]);
    *(short4v*)(ctxA + ((size_t)tstore * 32 + b) * 1024 + j) = o4;
}

// ---------------------------------------------------------------------------
// k_loop: wave-specialized persistent kernel (round-7/12 known-good, untouched).
// ---------------------------------------------------------------------------
#define ML_PITCH 1028
#define EL_PITCH 1032
#define ML_BYTES (16 * ML_PITCH * 4)
#define EL_BYTES (16 * EL_PITCH * 2)
#define DYN_BYTES (ML_BYTES + EL_BYTES)

__global__ void __launch_bounds__(256, 1)
k_loop(const u16* __restrict__ xg, const float* __restrict__ Mf,
       u16* __restrict__ ctxA, u16* __restrict__ hAll,
       u16* __restrict__ hb, float* __restrict__ hF, float* __restrict__ cF,
       float* __restrict__ pCtx, float* __restrict__ pMx, float* __restrict__ pSm,
       const float* __restrict__ enc, const float* __restrict__ Whh,
       const int* __restrict__ slen, float* __restrict__ out, u32* __restrict__ bar)
{
    const int bid = blockIdx.x, tid = threadIdx.x;
    const int wv = tid >> 6, l = tid & 63, lr = l & 15, lq = l >> 4;
    u32* slots = bar;

    extern __shared__ char smem[];
    float* Ml = (float*)smem;                 // [16][ML_PITCH]
    u16*   El = (u16*)(smem + ML_BYTES);      // [16][EL_PITCH]

    __shared__ float red[2][32][16];

    const int b_at = bid >> 3, ch = bid & 7, s0 = ch * 16;

    // ---- prologue ----
    short8 breg[16];
    if (wv < 2) {
        const float* wsrc = Whh + ((size_t)((lr >> 2) * 1024 + bid * 4 + (lr & 3))) * 1024
                                + wv * 512 + lq * 8;
#pragma unroll
        for (int ks = 0; ks < 16; ++ks)
            breg[ks] = cvt8(wsrc + ks * 32);
    }
    {   // M slice (fp32)
        int row = tid >> 4;
        const float* src = Mf + (size_t)(b_at * 128 + s0 + row) * 1024;
        float* dst = &Ml[row * ML_PITCH];
#pragma unroll
        for (int i = 0; i < 16; ++i) {
            int c = (tid & 15) * 4 + i * 64;
            *(f32x4*)(dst + c) = *(const f32x4*)(src + c);
        }
    }
    {   // enc slice (bf16)
        int row = tid >> 4;
        const float* src = enc + (size_t)(b_at * 128 + s0 + row) * 1024;
        u16* dst = &El[row * EL_PITCH];
#pragma unroll
        for (int i = 0; i < 16; ++i) {
            int c = (tid & 15) * 4 + i * 64;
            f32x4 v = *(const f32x4*)(src + c);
            short4v o;
            o[0]=(short)f2bf(v[0]); o[1]=(short)f2bf(v[1]);
            o[2]=(short)f2bf(v[2]); o[3]=(short)f2bf(v[3]);
            *(short4v*)(dst + c) = o;
        }
    }

    const int lb = tid & 31, lkk = (tid >> 5) - 4;
    const int lkidx = bid * 4 + lkk;
    float creg = 0.f;
    float xgv[4] = {0,0,0,0};
    if (tid >= 128) {
        creg = cF[lb * 1024 + lkidx];
#pragma unroll
        for (int g = 0; g < 4; ++g)
            xgv[g] = bf2f(xg[((size_t)lb) * 4096 + g * 1024 + lkidx]);   // t=0
    }
    int vlen = slen[b_at]; if (vlen < 1) vlen = 1;
    __syncthreads();

    for (int t = 0; t < 64; ++t) {
        if (t >= 1) bar_wait(slots, (u32)t, tid);

        if (t < 63 && wv < 2) {
            const u16* hrd = hb + (size_t)(t & 1) * (32 * 1024);
            const u16* p0 = hrd + lr * 1024 + wv * 512 + lq * 8;
            const u16* p1 = p0 + 16 * 1024;
            i32x4 a0b[16], a1b[16];
#pragma unroll
            for (int ks = 0; ks < 16; ++ks) {
                ldcc4i(&a0b[ks], p0 + ks * 32);
                ldcc4i(&a1b[ks], p1 + ks * 32);
            }
            f32x4 acc0 = {0,0,0,0}, acc1 = {0,0,0,0};
#pragma unroll
            for (int ks = 0; ks < 16; ++ks) {
                asm volatile("s_waitcnt vmcnt(%0)" :: "i"(30 - 2 * ks) : "memory");
                __builtin_amdgcn_sched_barrier(0);
                acc0 = __builtin_amdgcn_mfma_f32_16x16x32_bf16(as_s8(a0b[ks]), breg[ks], acc0, 0, 0, 0);
                acc1 = __builtin_amdgcn_mfma_f32_16x16x32_bf16(as_s8(a1b[ks]), breg[ks], acc1, 0, 0, 0);
            }
#pragma unroll
            for (int q = 0; q < 4; ++q) {
                red[wv][lq * 4 + q][lr] = acc0[q];
                red[wv][16 + lq * 4 + q][lr] = acc1[q];
            }
        }

        if (t >= 1 && wv >= 2) {
            const int w = wv - 2;
            const int lane = l;
            const float* hrow = hF + (size_t)(t & 1) * (32 * 1024) + b_at * 1024;
            f32x4 hreg[4];
            ldcc4f(&hreg[0], hrow + 0 * 256 + lane * 4);
            ldcc4f(&hreg[1], hrow + 1 * 256 + lane * 4);
            ldcc4f(&hreg[2], hrow + 2 * 256 + lane * 4);
            ldcc4f(&hreg[3], hrow + 3 * 256 + lane * 4);
            asm volatile("s_waitcnt vmcnt(0)" ::: "memory");
            __builtin_amdgcn_sched_barrier(0);
            float part[8];
#pragma unroll
            for (int r = 0; r < 8; ++r) {
                const float* mrow = &Ml[(w * 8 + r) * ML_PITCH];
                float s = 0.f;
#pragma unroll
                for (int c = 0; c < 4; ++c) {
                    f32x4 m4 = *(const f32x4*)(mrow + c * 256 + lane * 4);
                    s += m4[0]*hreg[c][0] + m4[1]*hreg[c][1] + m4[2]*hreg[c][2] + m4[3]*hreg[c][3];
                }
                part[r] = s;
            }
#pragma unroll
            for (int d = 1; d < 64; d <<= 1) {
#pragma unroll
                for (int r = 0; r < 8; ++r) part[r] += __shfl_xor(part[r], d);
            }
            int sgb = s0 + w * 8;
            float mc = -1e30f;
#pragma unroll
            for (int r = 0; r < 8; ++r) {
                part[r] = (sgb + r < vlen) ? part[r] : -1e30f;
                mc = fmaxf(mc, part[r]);
            }
            float e8[8]; float psum = 0.f;
#pragma unroll
            for (int r = 0; r < 8; ++r) {
                e8[r] = (part[r] > -1e29f) ? expf(part[r] - mc) : 0.f;
                psum += e8[r];
            }
            f32x4 ca[4] = {{0,0,0,0},{0,0,0,0},{0,0,0,0},{0,0,0,0}};
#pragma unroll
            for (int r = 0; r < 8; ++r) {
                float p = e8[r];
                const u16* erow = &El[(w * 8 + r) * EL_PITCH];
#pragma unroll
                for (int c = 0; c < 4; ++c) {
                    short4v e4 = *(const short4v*)(erow + c * 256 + lane * 4);
                    ca[c][0] += p * bf2f((u16)e4[0]);
                    ca[c][1] += p * bf2f((u16)e4[1]);
                    ca[c][2] += p * bf2f((u16)e4[2]);
                    ca[c][3] += p * bf2f((u16)e4[3]);
                }
            }
            float* pd = pCtx + (size_t)(t & 3) * (32 * 16 * 1024)
                             + (size_t)(b_at * 16 + ch * 2 + w) * 1024;
#pragma unroll
            for (int c = 0; c < 4; ++c) {
                union { f32x4 v; u64 q[2]; } cu; cu.v = ca[c];
                u64* p = (u64*)(pd + c * 256 + lane * 4);
                stg_u64(p, cu.q[0]);
                stg_u64(p + 1, cu.q[1]);
            }
            if (lane == 0) {
                stg_f32(&pMx[(size_t)(t & 3) * 512 + b_at * 16 + ch * 2 + w], mc);
                stg_f32(&pSm[(size_t)(t & 3) * 512 + b_at * 16 + ch * 2 + w], psum);
            }
        }
        __syncthreads();

        if (t < 63 && tid >= 128) {
            float G[4];
#pragma unroll
            for (int g = 0; g < 4; ++g) {
                int n = g * 4 + lkk;
                G[g] = red[0][lb][n] + red[1][lb][n] + xgv[g];
            }
            float iS = sigm(G[0]), fS = sigm(G[1]), gT = tanhf(G[2]), oS = sigm(G[3]);
            float cn = fS * creg + iS * gT;
            float hn = oS * tanhf(cn);
            creg = cn;
            u16 h16 = f2bf(hn);
            int sl = (t + 1) & 1;
            stg_f32(&hF[(size_t)sl * (32 * 1024) + lb * 1024 + lkidx], hn);
            stg_u16(&hb[(size_t)sl * (32 * 1024) + lb * 1024 + lkidx], h16);
            hAll[((size_t)t * 32 + lb) * 1024 + lkidx] = h16;
        }

        bar_arrive(slots, (u32)(t + 1), bid, tid);

        if (t >= 2)
            combine16(b_at, ch, t - 2, tid, (t - 1) & 3, pCtx, pMx, pSm, ctxA);
        if (t < 62 && tid >= 128) {
#pragma unroll
            for (int g = 0; g < 4; ++g)
                xgv[g] = bf2f(xg[((size_t)(t + 1) * 32 + lb) * 4096 + g * 1024 + lkidx]);
        }
    }

    bar_wait(slots, 64u, tid);
    combine16(b_at, ch, 62, tid, 3, pCtx, pMx, pSm, ctxA);
    if (bid >= 32 && bid < 64) {
        int b = bid - 32, j = tid * 4;
#pragma unroll
        for (int i = 0; i < 4; ++i)
            out[2064384 + b * 1024 + j + i] = ldg_f32(&hF[(size_t)1 * (32 * 1024) + b * 1024 + j + i]);
    }
    if (tid >= 128)
        out[2064384 + 32768 + lb * 1024 + lkidx] = creg;
}

// ---------------------------------------------------------------------------
// k_out: output GEMM, tile 256x32, B-panel (32 rows x 2048 K) LDS-resident.
// ---------------------------------------------------------------------------
__global__ void __launch_bounds__(512, 1)
k_out(const u16* __restrict__ ctxA, const u16* __restrict__ hAll,
      const float* __restrict__ Wao, float* __restrict__ out)
{
    extern __shared__ char Bl[];
    const int tid = threadIdx.x;
    const int wv = tid >> 6, l = tid & 63, lr = l & 15, lq = l >> 4;
    const int bx = blockIdx.x;
    const int mt = bx & 7, nt = bx >> 3;   // 8 m-tiles x 32 n-tiles

    // stage B: Wao rows [nt*32, +32) x 2048, fp32 -> bf16, swizzled
    for (int u = tid; u < 8192; u += 512) {
        int row = u >> 8, c8 = (u & 255) * 8;
        *(short8*)(Bl + swz4k(row, c8 * 2)) = cvt8(Wao + (size_t)(nt * 32 + row) * 2048 + c8);
    }
    __syncthreads();

    const int r0 = mt * 256 + wv * 32;
    int rA0 = r0 + lr;       if (rA0 > 2015) rA0 = 2015;
    int rA1 = r0 + 16 + lr;  if (rA1 > 2015) rA1 = 2015;
    const u16* ac0 = ctxA + (size_t)rA0 * 1024 + lq * 8;
    const u16* ah0 = hAll + (size_t)rA0 * 1024 + lq * 8;
    const u16* ac1 = ctxA + (size_t)rA1 * 1024 + lq * 8;
    const u16* ah1 = hAll + (size_t)rA1 * 1024 + lq * 8;

    short8 aq0[4], aq1[4];
#pragma unroll
    for (int d = 0; d < 4; ++d) {
        aq0[d] = *(const short8*)(ac0 + d * 32);
        aq1[d] = *(const short8*)(ac1 + d * 32);
    }
    f32x4 acc[2][2];
#pragma unroll
    for (int rg = 0; rg < 2; ++rg)
#pragma unroll
        for (int nf = 0; nf < 2; ++nf) acc[rg][nf] = (f32x4){0.f, 0.f, 0.f, 0.f};

#pragma unroll
    for (int k = 0; k < 64; ++k) {
        short8 av0 = aq0[k & 3], av1 = aq1[k & 3];
        if (k + 4 < 64) {
            int kn = k + 4;
            if (kn < 32) {
                aq0[k & 3] = *(const short8*)(ac0 + kn * 32);
                aq1[k & 3] = *(const short8*)(ac1 + kn * 32);
            } else {
                aq0[k & 3] = *(const short8*)(ah0 + (kn - 32) * 32);
                aq1[k & 3] = *(const short8*)(ah1 + (kn - 32) * 32);
            }
        }
#pragma unroll
        for (int nf = 0; nf < 2; ++nf) {
            short8 bv = *(const short8*)(Bl + swz4k(nf * 16 + lr, (lq * 8 + k * 32) * 2));
            acc[0][nf] = __builtin_amdgcn_mfma_f32_16x16x32_bf16(av0, bv, acc[0][nf], 0, 0, 0);
            acc[1][nf] = __builtin_amdgcn_mfma_f32_16x16x32_bf16(av1, bv, acc[1][nf], 0, 0, 0);
        }
    }
#pragma unroll
    for (int rg = 0; rg < 2; ++rg)
#pragma unroll
    for (int nf = 0; nf < 2; ++nf) {
        int n = nt * 32 + nf * 16 + lr;
#pragma unroll
        for (int q = 0; q < 4; ++q) {
            int rr = r0 + rg * 16 + lq * 4 + q;
            if (rr < 2016) {
                int t = rr >> 5, b = rr & 31;
                out[(size_t)b * 64512 + t * 1024 + n] = tanhf(acc[rg][nf][q]);
            }
        }
    }
}

// ---------------------------------------------------------------------------
extern "C" void kernel_launch(void* const* d_in, const int* in_sizes, int n_in,
                              void* d_out, int out_size, void* d_ws, size_t ws_size,
                              hipStream_t stream)
{
    (void)in_sizes; (void)n_in; (void)out_size; (void)ws_size;
    const int*   tgt  = (const int*)d_in[0];
    const float* h0   = (const float*)d_in[1];
    const float* c0   = (const float*)d_in[2];
    const float* enc  = (const float*)d_in[3];
    const int*   slen = (const int*)d_in[4];
    const float* emb  = (const float*)d_in[5];
    const float* Wih  = (const float*)d_in[6];
    const float* Whh  = (const float*)d_in[7];
    const float* bih  = (const float*)d_in[8];
    const float* bhh  = (const float*)d_in[9];
    const float* Wai  = (const float*)d_in[10];
    const float* Wao  = (const float*)d_in[11];
    float* out = (float*)d_out;

    char* ws = (char*)d_ws;
    size_t off = 0;
    auto alloc = [&](size_t bytes) -> char* {
        char* p = ws + off; off += (bytes + 255) & ~(size_t)255; return p;
    };
    u16*   enc16 = (u16*)  alloc(4096UL * 1024 * 2);
    u16*   xrow  = (u16*)  alloc(2016UL * 1024 * 2);
    u16*   WT    = (u16*)  alloc(1024UL * 1024 * 2);
    u16*   xg    = (u16*)  alloc(2016UL * 4096 * 2);
    float* Mf    = (float*)alloc(4096UL * 1024 * 4);
    u16*   hb    = (u16*)  alloc(2UL * 32 * 1024 * 2);
    float* hF    = (float*)alloc(2UL * 32 * 1024 * 4);
    float* cF    = (float*)alloc(32UL * 1024 * 4);
    u16*   hAll  = (u16*)  alloc(2016UL * 1024 * 2);
    u16*   ctxA  = (u16*)  alloc(2016UL * 1024 * 2);
    float* pCtx  = (float*)alloc(4UL * 32 * 16 * 1024 * 4);
    float* pMx   = (float*)alloc(4UL * 512 * 4);
    float* pSm   = (float*)alloc(4UL * 512 * 4);
    u32*   bar   = (u32*)  alloc(2048);

    static int lds_set = 0;
    if (!lds_set) {
        (void)hipFuncSetAttribute((const void*)k_loop,
                                  hipFuncAttributeMaxDynamicSharedMemorySize, DYN_BYTES);
        (void)hipFuncSetAttribute((const void*)k_mm,
                                  hipFuncAttributeMaxDynamicSharedMemorySize, 131072);
        (void)hipFuncSetAttribute((const void*)k_out,
                                  hipFuncAttributeMaxDynamicSharedMemorySize, 131072);
        lds_set = 1;
    }

    hipMemsetAsync(bar, 0, 2048, stream);
    hipLaunchKernelGGL(k_prep, dim3(6400), dim3(256), 0, stream,
                       enc, enc16, tgt, emb, xrow, Wai, WT, h0, c0, cF, hb);
    hipLaunchKernelGGL(k_mm, dim3(768), dim3(512), 131072, stream,
                       xrow, Wih, bih, bhh, xg, enc16, WT, Mf);

    void* kargs[] = { (void*)&xg, (void*)&Mf, (void*)&ctxA, (void*)&hAll, (void*)&hb,
                      (void*)&hF, (void*)&cF, (void*)&pCtx, (void*)&pMx, (void*)&pSm,
                      (void*)&enc, (void*)&Whh, (void*)&slen, (void*)&out, (void*)&bar };
    hipLaunchCooperativeKernel((const void*)k_loop, dim3(256), dim3(256), kargs, DYN_BYTES, stream);

    hipLaunchKernelGGL(k_out, dim3(256), dim3(512), 131072, stream, ctxA, hAll, Wao, out);
}